// Round 2
// baseline (1183.500 us; speedup 1.0000x reference)
//
#include <hip/hip_runtime.h>

// QBN_GRU_Base on MI355X.
// Ternary bottlenecks (dim 8) make the recurrence finite-state:
//   xq, q in {-1,0,1}^8 -> 6561 codes. Memoize
//     GI[code][64]   = xq@wih.T + bih            (packed [i*4+{r,z,n,pad}])
//     GHM[code][64]  = {m@whh.T + bhh, m}        (packed [i*4+{r,z,n,m}], row 6561 = h0 state)
//     Y[code][16]    = tanh(m@act_w.T + act_b)
// Scan step = 2 table-row loads + gates + m2q (640 MAC) across 16 lanes/elem.
// R3/R4 change (latency-bound scan, VALUBusy 17%, VGPR_Count 56):
//   - __launch_bounds__(64, 1): occupancy is irrelevant (512 waves on 1024
//     SIMDs); the old reg budget forced the 48 m2q weight floats to be
//     reloaded from memory inside the t-loop, fully exposed at 1 wave/SIMD.
//   - batch the 16 ds_bpermute broadcasts per layer into a temp array before
//     the fma chain (identical arithmetic order -> bit-exact).
//   - digit reduction: 4-round DPP row_ror all-reduce (VALU pipe) instead of
//     8 ds_bpermute + tree. Summands are exact integers (digit*3^k*256), so
//     order is irrelevant; lanes 8..15 carry a zero scale.
// (R4 = R3 resubmitted: round-3 bench was an infra failure, no measurement.)
// Numerics: XLA/Eigen rational tanh, logistic = 0.5+0.5*tanh(0.5x), fma dots —
// all float expressions identical to the absmax==0.0 round-1 kernel.

#define T_DIM 512
#define B_DIM 2048
#define NELEM (T_DIM * B_DIM)

__device__ __forceinline__ float tanh_xla(float x) {
  // Eigen/XLA generic_fast_tanh_float
  const float kClamp = 7.99881172180175781f;
  float xc = fminf(fmaxf(x, -kClamp), kClamp);
  float x2 = xc * xc;
  float p = fmaf(x2, -2.76076847742355e-16f, 2.00018790482477e-13f);
  p = fmaf(x2, p, -8.60467152213735e-11f);
  p = fmaf(x2, p, 5.12229709037114e-08f);
  p = fmaf(x2, p, 1.48572235717979e-05f);
  p = fmaf(x2, p, 6.37261928875436e-04f);
  p = fmaf(x2, p, 4.89352455891786e-03f);
  p = xc * p;
  float q = fmaf(x2, 1.19825839466702e-06f, 1.18534705686654e-04f);
  q = fmaf(x2, q, 2.26843463243900e-03f);
  q = fmaf(x2, q, 4.89352518554385e-03f);
  float r = p / q;
  return (fabsf(x) < 0.0004f) ? x : r;
}

__device__ __forceinline__ float sigmoid_xla(float x) {
  return 0.5f + 0.5f * tanh_xla(0.5f * x);
}

__device__ __forceinline__ int ternary_digit(float v) {
  float soft = 1.5f * tanh_xla(v) + 0.5f * tanh_xla(-3.0f * v);
  return (int)rintf(soft) + 1;
}

// ---------------- K1: obs encoder -> xcode[T*B] ----------------
__global__ __launch_bounds__(256) void k_obs(
    const float* __restrict__ x,
    const float* __restrict__ w0, const float* __restrict__ b0,
    const float* __restrict__ w1, const float* __restrict__ b1,
    const float* __restrict__ w2, const float* __restrict__ b2,
    unsigned short* __restrict__ xcodes) {
  int e = blockIdx.x * 256 + threadIdx.x;  // grid is exact
  const float* xr = x + (size_t)e * 64;
  float xv[64];
#pragma unroll
  for (int j = 0; j < 64; j += 4) {
    float4 v = *reinterpret_cast<const float4*>(xr + j);
    xv[j] = v.x; xv[j + 1] = v.y; xv[j + 2] = v.z; xv[j + 3] = v.w;
  }
  float h1[28];
#pragma unroll
  for (int k = 0; k < 28; ++k) {
    float acc = 0.0f;
#pragma unroll
    for (int j = 0; j < 64; ++j) acc = fmaf(w0[k * 64 + j], xv[j], acc);
    h1[k] = tanh_xla(acc + b0[k]);
  }
  float h2[28];
#pragma unroll
  for (int k = 0; k < 28; ++k) {
    float acc = 0.0f;
#pragma unroll
    for (int j = 0; j < 28; ++j) acc = fmaf(w1[k * 28 + j], h1[j], acc);
    h2[k] = tanh_xla(acc + b1[k]);
  }
  const int p3[8] = {1, 3, 9, 27, 81, 243, 729, 2187};
  unsigned code = 0;
#pragma unroll
  for (int k = 0; k < 8; ++k) {
    float acc = 0.0f;
#pragma unroll
    for (int j = 0; j < 28; ++j) acc = fmaf(w2[k * 28 + j], h2[j], acc);
    code += (unsigned)(ternary_digit(acc + b2[k]) * p3[k]);
  }
  xcodes[e] = (unsigned short)code;
}

// ---------------- K2: GI table [6561][64] ----------------
__global__ __launch_bounds__(256) void k_gi(
    const float* __restrict__ wih, const float* __restrict__ bih,
    float* __restrict__ gip) {
  int c = blockIdx.x * 256 + threadIdx.x;
  if (c >= 6561) return;
  float q[8];
  unsigned cc = (unsigned)c;
#pragma unroll
  for (int k = 0; k < 8; ++k) { q[k] = (float)((int)(cc % 3u) - 1); cc /= 3u; }
#pragma unroll
  for (int i = 0; i < 16; ++i) {
    float gr = 0.f, gz = 0.f, gn = 0.f;
#pragma unroll
    for (int j = 0; j < 8; ++j) {
      gr = fmaf(wih[i * 8 + j], q[j], gr);
      gz = fmaf(wih[(16 + i) * 8 + j], q[j], gz);
      gn = fmaf(wih[(32 + i) * 8 + j], q[j], gn);
    }
    float4 o;
    o.x = gr + bih[i]; o.y = gz + bih[16 + i]; o.z = gn + bih[32 + i]; o.w = 0.f;
    *reinterpret_cast<float4*>(gip + (size_t)c * 64 + i * 4) = o;
  }
}

// ---------------- K3: GHM [6562][64] + Y [6561][16] ----------------
__global__ __launch_bounds__(256) void k_mtab(
    const float* __restrict__ q2m_w0, const float* __restrict__ q2m_b0,
    const float* __restrict__ q2m_w1, const float* __restrict__ q2m_b1,
    const float* __restrict__ q2m_w2, const float* __restrict__ q2m_b2,
    const float* __restrict__ whh, const float* __restrict__ bhh,
    const float* __restrict__ act_w, const float* __restrict__ act_b,
    float* __restrict__ ghm, float* __restrict__ ytab) {
  int c = blockIdx.x * 256 + threadIdx.x;
  if (c > 6561) return;
  float m[16];
  if (c == 6561) {
#pragma unroll
    for (int i = 0; i < 16; ++i) m[i] = 0.0f;  // h0 = 0
  } else {
    float q[8];
    unsigned cc = (unsigned)c;
#pragma unroll
    for (int k = 0; k < 8; ++k) { q[k] = (float)((int)(cc % 3u) - 1); cc /= 3u; }
    float a[16];
#pragma unroll
    for (int i = 0; i < 16; ++i) {
      float acc = 0.f;
#pragma unroll
      for (int j = 0; j < 8; ++j) acc = fmaf(q2m_w0[i * 8 + j], q[j], acc);
      a[i] = tanh_xla(acc + q2m_b0[i]);
    }
    float d[16];
#pragma unroll
    for (int i = 0; i < 16; ++i) {
      float acc = 0.f;
#pragma unroll
      for (int j = 0; j < 16; ++j) acc = fmaf(q2m_w1[i * 16 + j], a[j], acc);
      d[i] = tanh_xla(acc + q2m_b1[i]);
    }
#pragma unroll
    for (int i = 0; i < 16; ++i) {
      float acc = 0.f;
#pragma unroll
      for (int j = 0; j < 16; ++j) acc = fmaf(q2m_w2[i * 16 + j], d[j], acc);
      m[i] = tanh_xla(acc + q2m_b2[i]);
    }
  }
#pragma unroll
  for (int i = 0; i < 16; ++i) {
    float gr = 0.f, gz = 0.f, gn = 0.f;
#pragma unroll
    for (int j = 0; j < 16; ++j) {
      gr = fmaf(whh[i * 16 + j], m[j], gr);
      gz = fmaf(whh[(16 + i) * 16 + j], m[j], gz);
      gn = fmaf(whh[(32 + i) * 16 + j], m[j], gn);
    }
    float4 o;
    o.x = gr + bhh[i]; o.y = gz + bhh[16 + i]; o.z = gn + bhh[32 + i]; o.w = m[i];
    *reinterpret_cast<float4*>(ghm + (size_t)c * 64 + i * 4) = o;
  }
  if (c < 6561) {
#pragma unroll
    for (int i = 0; i < 16; ++i) {
      float acc = 0.f;
#pragma unroll
      for (int j = 0; j < 16; ++j) acc = fmaf(act_w[i * 16 + j], m[j], acc);
      ytab[(size_t)c * 16 + i] = tanh_xla(acc + act_b[i]);
    }
  }
}

// ---------------- K4: the scan. 16 lanes per batch element ----------------
__device__ __forceinline__ float bcast16(int base4, int j, float v) {
  // broadcast lane ((lane&~15)+j)'s v to all lanes of the 16-group
  return __int_as_float(
      __builtin_amdgcn_ds_bpermute(base4 + 4 * j, __float_as_int(v)));
}

// add the row_ror:<N>-moved copy of v (16-lane row rotation, VALU pipe)
#define DPP_ROR_ADD(v, CTRL)                                               \
  v += __int_as_float(__builtin_amdgcn_update_dpp(                         \
      0, __float_as_int(v), (CTRL), 0xF, 0xF, true))

__global__ __launch_bounds__(64, 1) void k_scan(
    const unsigned short* __restrict__ xcodes,
    const float* __restrict__ ghm,  // [6562][64]
    const float* __restrict__ gip,  // [6561][64]
    const float* __restrict__ m2q_w0, const float* __restrict__ m2q_b0,
    const float* __restrict__ m2q_w1, const float* __restrict__ m2q_b1,
    const float* __restrict__ m2q_w2, const float* __restrict__ m2q_b2,
    unsigned short* __restrict__ qcodes) {
  int lane = threadIdx.x & 15;
  int b = (blockIdx.x * 64 + threadIdx.x) >> 4;  // 0..2047
  int base4 = (threadIdx.x & 48) << 2;           // bpermute byte addr of group lane 0
  int lane16 = lane * 16;                        // byte offset of this lane's float4

  // per-lane m2q weight rows (kept resident: __launch_bounds__(64,1) lifts the
  // VGPR cap; occupancy is irrelevant for this latency-bound 512-wave grid)
  float w0r[16], w1r[16], w2r[16];
#pragma unroll
  for (int j = 0; j < 16; j += 4) {
    float4 a = *reinterpret_cast<const float4*>(m2q_w0 + lane * 16 + j);
    w0r[j] = a.x; w0r[j + 1] = a.y; w0r[j + 2] = a.z; w0r[j + 3] = a.w;
    float4 bq = *reinterpret_cast<const float4*>(m2q_w1 + lane * 16 + j);
    w1r[j] = bq.x; w1r[j + 1] = bq.y; w1r[j + 2] = bq.z; w1r[j + 3] = bq.w;
    float4 cq = *reinterpret_cast<const float4*>(m2q_w2 + (lane & 7) * 16 + j);
    w2r[j] = cq.x; w2r[j + 1] = cq.y; w2r[j + 2] = cq.z; w2r[j + 3] = cq.w;
  }
  float b0l = m2q_b0[lane], b1l = m2q_b1[lane], b2l = m2q_b2[lane & 7];
  // digit weight: 3^(lane&7) * 256 as float (exact); zero on lanes 8..15 so a
  // full 16-lane rotate-reduce counts each digit exactly once
  int p3i = 1;
  for (int k = 0; k < (lane & 7); ++k) p3i *= 3;
  float w3f = (lane < 8) ? (float)(p3i * 256) : 0.0f;
  const int kOffBias = 3280 * 256;  // sum of 3^k*256, k=0..7

  const char* ghmB = (const char*)ghm;
  const char* gipB = (const char*)gip;

  int qoff = 6561 * 256;  // byte offset of initial-state row
  unsigned xc = xcodes[b];
  float4 i4 = *reinterpret_cast<const float4*>(gipB + (unsigned)(((int)xc << 8) + lane16));

  for (int t = 0; t < T_DIM; ++t) {
    float4 g4 = *reinterpret_cast<const float4*>(ghmB + (unsigned)(qoff + lane16));
    // prefetch next step's GI row (independent of qprev chain)
    int tn = (t + 1 < T_DIM) ? t + 1 : T_DIM - 1;
    unsigned xcn = xcodes[tn * B_DIM + b];
    float4 i4n = *reinterpret_cast<const float4*>(gipB + (unsigned)(((int)xcn << 8) + lane16));

    float r = sigmoid_xla(i4.x + g4.x);
    float z = sigmoid_xla(i4.y + g4.y);
    float n = tanh_xla(fmaf(r, g4.z, i4.z));
    float h = (1.0f - z) * n + z * g4.w;

    // layer 0: batch all 16 broadcasts, then the (order-preserving) fma chain
    float hv[16];
#pragma unroll
    for (int j = 0; j < 16; ++j) hv[j] = bcast16(base4, j, h);
    float acc = 0.f;
#pragma unroll
    for (int j = 0; j < 16; ++j) acc = fmaf(w0r[j], hv[j], acc);
    float t0 = tanh_xla(acc + b0l);

    float tv0[16];
#pragma unroll
    for (int j = 0; j < 16; ++j) tv0[j] = bcast16(base4, j, t0);
    acc = 0.f;
#pragma unroll
    for (int j = 0; j < 16; ++j) acc = fmaf(w1r[j], tv0[j], acc);
    float t1 = tanh_xla(acc + b1l);

    float tv1[16];
#pragma unroll
    for (int j = 0; j < 16; ++j) tv1[j] = bcast16(base4, j, t1);
    acc = 0.f;
#pragma unroll
    for (int j = 0; j < 16; ++j) acc = fmaf(w2r[j], tv1[j], acc);

    // ternary digit as float, pre-scaled by 3^k*256 (exact integers in fp32)
    float s = acc + b2l;
    float soft = 1.5f * tanh_xla(s) + 0.5f * tanh_xla(-3.0f * s);
    float st = rintf(soft) * w3f;  // in {-1,0,1} * 3^k*256 (0 on lanes 8..15)
    // exact-integer all-reduce across the 16-lane row: 4 DPP rotate+add rounds
    DPP_ROR_ADD(st, 0x128);  // row_ror:8
    DPP_ROR_ADD(st, 0x124);  // row_ror:4
    DPP_ROR_ADD(st, 0x122);  // row_ror:2
    DPP_ROR_ADD(st, 0x121);  // row_ror:1
    qoff = (int)st + kOffBias;  // byte offset = qcode*256

    if (lane == 0) qcodes[t * B_DIM + b] = (unsigned short)((unsigned)qoff >> 8);
    i4 = i4n;
  }
}

// ---------------- K5: output gather out[e] = Y[qcode[e]] ----------------
__global__ __launch_bounds__(256) void k_out(
    const unsigned short* __restrict__ qcodes,
    const float* __restrict__ ytab,
    float* __restrict__ out) {
  int i = blockIdx.x * 256 + threadIdx.x;  // over NELEM*4 float4s, grid exact
  int e = i >> 2, sub = i & 3;
  unsigned c = qcodes[e];
  float4 y = *reinterpret_cast<const float4*>(ytab + (size_t)c * 16 + sub * 4);
  reinterpret_cast<float4*>(out)[i] = y;
}

extern "C" void kernel_launch(void* const* d_in, const int* in_sizes, int n_in,
                              void* d_out, int out_size, void* d_ws, size_t ws_size,
                              hipStream_t stream) {
  (void)in_sizes; (void)n_in; (void)out_size; (void)ws_size;
  const float* x       = (const float*)d_in[0];
  const float* obs_w0  = (const float*)d_in[1];
  const float* obs_b0  = (const float*)d_in[2];
  const float* obs_w1  = (const float*)d_in[3];
  const float* obs_b1  = (const float*)d_in[4];
  const float* obs_w2  = (const float*)d_in[5];
  const float* obs_b2  = (const float*)d_in[6];
  const float* gru_wih = (const float*)d_in[7];
  const float* gru_whh = (const float*)d_in[8];
  const float* gru_bih = (const float*)d_in[9];
  const float* gru_bhh = (const float*)d_in[10];
  const float* m2q_w0  = (const float*)d_in[11];
  const float* m2q_b0  = (const float*)d_in[12];
  const float* m2q_w1  = (const float*)d_in[13];
  const float* m2q_b1  = (const float*)d_in[14];
  const float* m2q_w2  = (const float*)d_in[15];
  const float* m2q_b2  = (const float*)d_in[16];
  const float* q2m_w0  = (const float*)d_in[17];
  const float* q2m_b0  = (const float*)d_in[18];
  const float* q2m_w1  = (const float*)d_in[19];
  const float* q2m_b1  = (const float*)d_in[20];
  const float* q2m_w2  = (const float*)d_in[21];
  const float* q2m_b2  = (const float*)d_in[22];
  const float* act_w   = (const float*)d_in[23];
  const float* act_b   = (const float*)d_in[24];

  char* ws = (char*)d_ws;
  unsigned short* xcodes = (unsigned short*)(ws);
  unsigned short* qcodes = (unsigned short*)(ws + (2u << 20));
  float* gip  = (float*)(ws + (4u << 20));
  float* ghm  = (float*)(ws + (6u << 20));
  float* ytab = (float*)(ws + (8u << 20));

  k_gi<<<26, 256, 0, stream>>>(gru_wih, gru_bih, gip);
  k_mtab<<<26, 256, 0, stream>>>(q2m_w0, q2m_b0, q2m_w1, q2m_b1, q2m_w2, q2m_b2,
                                 gru_whh, gru_bhh, act_w, act_b, ghm, ytab);
  k_obs<<<NELEM / 256, 256, 0, stream>>>(x, obs_w0, obs_b0, obs_w1, obs_b1,
                                         obs_w2, obs_b2, xcodes);
  k_scan<<<(B_DIM * 16) / 64, 64, 0, stream>>>(xcodes, ghm, gip,
                                               m2q_w0, m2q_b0, m2q_w1, m2q_b1,
                                               m2q_w2, m2q_b2, qcodes);
  k_out<<<(NELEM * 4) / 256, 256, 0, stream>>>(qcodes, ytab, (float*)d_out);
}

// Round 3
// 1100.147 us; speedup vs baseline: 1.0758x; 1.0758x over previous
//
#include <hip/hip_runtime.h>

// QBN_GRU_Base on MI355X.
// Ternary bottlenecks (dim 8) make the recurrence finite-state:
//   xq, q in {-1,0,1}^8 -> 6561 codes. Memoize
//     GI[code][64]   = xq@wih.T + bih            (packed [i*4+{r,z,n,pad}])
//     GHM[code][64]  = {m@whh.T + bhh, m}        (packed [i*4+{r,z,n,m}], row 6561 = h0 state)
//     Y[code][16]    = tanh(m@act_w.T + act_b)
// Scan step = 2 table-row loads + gates + m2q (640 MAC) across 16 lanes/elem.
// R5 change: the scan's wall time is 512 x per-step dependent-chain latency
// (occupancy is irrelevant; each chain is serial). R2 counters showed
// VGPR_Count=48 -> the compiler allocated ~1 temp for the 16 per-layer
// ds_bpermute broadcasts and serialized them (bperm->wait->fma x16 = ~2400cy
// of exposed LDS latency per step, matching the 3100cy/step measurement).
// Fix: force-batch each 16-way broadcast in ONE asm volatile block with 16
// distinct early-clobber "=&v" outputs (offset:0..60 on a single base index)
// and a single s_waitcnt lgkmcnt(0). Bit-identical bpermute semantics,
// fma-chain order unchanged -> absmax must stay 0.0.
// Digit reduction stays the 4-round DPP row_ror all-reduce (exact integers,
// order-free). Numerics: XLA/Eigen rational tanh, logistic =
// 0.5+0.5*tanh(0.5x), fma dots — identical float expressions throughout.

#define T_DIM 512
#define B_DIM 2048
#define NELEM (T_DIM * B_DIM)

__device__ __forceinline__ float tanh_xla(float x) {
  // Eigen/XLA generic_fast_tanh_float
  const float kClamp = 7.99881172180175781f;
  float xc = fminf(fmaxf(x, -kClamp), kClamp);
  float x2 = xc * xc;
  float p = fmaf(x2, -2.76076847742355e-16f, 2.00018790482477e-13f);
  p = fmaf(x2, p, -8.60467152213735e-11f);
  p = fmaf(x2, p, 5.12229709037114e-08f);
  p = fmaf(x2, p, 1.48572235717979e-05f);
  p = fmaf(x2, p, 6.37261928875436e-04f);
  p = fmaf(x2, p, 4.89352455891786e-03f);
  p = xc * p;
  float q = fmaf(x2, 1.19825839466702e-06f, 1.18534705686654e-04f);
  q = fmaf(x2, q, 2.26843463243900e-03f);
  q = fmaf(x2, q, 4.89352518554385e-03f);
  float r = p / q;
  return (fabsf(x) < 0.0004f) ? x : r;
}

__device__ __forceinline__ float sigmoid_xla(float x) {
  return 0.5f + 0.5f * tanh_xla(0.5f * x);
}

__device__ __forceinline__ int ternary_digit(float v) {
  float soft = 1.5f * tanh_xla(v) + 0.5f * tanh_xla(-3.0f * v);
  return (int)rintf(soft) + 1;
}

// ---------------- K1: obs encoder -> xcode[T*B] ----------------
__global__ __launch_bounds__(256) void k_obs(
    const float* __restrict__ x,
    const float* __restrict__ w0, const float* __restrict__ b0,
    const float* __restrict__ w1, const float* __restrict__ b1,
    const float* __restrict__ w2, const float* __restrict__ b2,
    unsigned short* __restrict__ xcodes) {
  int e = blockIdx.x * 256 + threadIdx.x;  // grid is exact
  const float* xr = x + (size_t)e * 64;
  float xv[64];
#pragma unroll
  for (int j = 0; j < 64; j += 4) {
    float4 v = *reinterpret_cast<const float4*>(xr + j);
    xv[j] = v.x; xv[j + 1] = v.y; xv[j + 2] = v.z; xv[j + 3] = v.w;
  }
  float h1[28];
#pragma unroll
  for (int k = 0; k < 28; ++k) {
    float acc = 0.0f;
#pragma unroll
    for (int j = 0; j < 64; ++j) acc = fmaf(w0[k * 64 + j], xv[j], acc);
    h1[k] = tanh_xla(acc + b0[k]);
  }
  float h2[28];
#pragma unroll
  for (int k = 0; k < 28; ++k) {
    float acc = 0.0f;
#pragma unroll
    for (int j = 0; j < 28; ++j) acc = fmaf(w1[k * 28 + j], h1[j], acc);
    h2[k] = tanh_xla(acc + b1[k]);
  }
  const int p3[8] = {1, 3, 9, 27, 81, 243, 729, 2187};
  unsigned code = 0;
#pragma unroll
  for (int k = 0; k < 8; ++k) {
    float acc = 0.0f;
#pragma unroll
    for (int j = 0; j < 28; ++j) acc = fmaf(w2[k * 28 + j], h2[j], acc);
    code += (unsigned)(ternary_digit(acc + b2[k]) * p3[k]);
  }
  xcodes[e] = (unsigned short)code;
}

// ---------------- K2: GI table [6561][64] ----------------
__global__ __launch_bounds__(256) void k_gi(
    const float* __restrict__ wih, const float* __restrict__ bih,
    float* __restrict__ gip) {
  int c = blockIdx.x * 256 + threadIdx.x;
  if (c >= 6561) return;
  float q[8];
  unsigned cc = (unsigned)c;
#pragma unroll
  for (int k = 0; k < 8; ++k) { q[k] = (float)((int)(cc % 3u) - 1); cc /= 3u; }
#pragma unroll
  for (int i = 0; i < 16; ++i) {
    float gr = 0.f, gz = 0.f, gn = 0.f;
#pragma unroll
    for (int j = 0; j < 8; ++j) {
      gr = fmaf(wih[i * 8 + j], q[j], gr);
      gz = fmaf(wih[(16 + i) * 8 + j], q[j], gz);
      gn = fmaf(wih[(32 + i) * 8 + j], q[j], gn);
    }
    float4 o;
    o.x = gr + bih[i]; o.y = gz + bih[16 + i]; o.z = gn + bih[32 + i]; o.w = 0.f;
    *reinterpret_cast<float4*>(gip + (size_t)c * 64 + i * 4) = o;
  }
}

// ---------------- K3: GHM [6562][64] + Y [6561][16] ----------------
__global__ __launch_bounds__(256) void k_mtab(
    const float* __restrict__ q2m_w0, const float* __restrict__ q2m_b0,
    const float* __restrict__ q2m_w1, const float* __restrict__ q2m_b1,
    const float* __restrict__ q2m_w2, const float* __restrict__ q2m_b2,
    const float* __restrict__ whh, const float* __restrict__ bhh,
    const float* __restrict__ act_w, const float* __restrict__ act_b,
    float* __restrict__ ghm, float* __restrict__ ytab) {
  int c = blockIdx.x * 256 + threadIdx.x;
  if (c > 6561) return;
  float m[16];
  if (c == 6561) {
#pragma unroll
    for (int i = 0; i < 16; ++i) m[i] = 0.0f;  // h0 = 0
  } else {
    float q[8];
    unsigned cc = (unsigned)c;
#pragma unroll
    for (int k = 0; k < 8; ++k) { q[k] = (float)((int)(cc % 3u) - 1); cc /= 3u; }
    float a[16];
#pragma unroll
    for (int i = 0; i < 16; ++i) {
      float acc = 0.f;
#pragma unroll
      for (int j = 0; j < 8; ++j) acc = fmaf(q2m_w0[i * 8 + j], q[j], acc);
      a[i] = tanh_xla(acc + q2m_b0[i]);
    }
    float d[16];
#pragma unroll
    for (int i = 0; i < 16; ++i) {
      float acc = 0.f;
#pragma unroll
      for (int j = 0; j < 16; ++j) acc = fmaf(q2m_w1[i * 16 + j], a[j], acc);
      d[i] = tanh_xla(acc + q2m_b1[i]);
    }
#pragma unroll
    for (int i = 0; i < 16; ++i) {
      float acc = 0.f;
#pragma unroll
      for (int j = 0; j < 16; ++j) acc = fmaf(q2m_w2[i * 16 + j], d[j], acc);
      m[i] = tanh_xla(acc + q2m_b2[i]);
    }
  }
#pragma unroll
  for (int i = 0; i < 16; ++i) {
    float gr = 0.f, gz = 0.f, gn = 0.f;
#pragma unroll
    for (int j = 0; j < 16; ++j) {
      gr = fmaf(whh[i * 16 + j], m[j], gr);
      gz = fmaf(whh[(16 + i) * 16 + j], m[j], gz);
      gn = fmaf(whh[(32 + i) * 16 + j], m[j], gn);
    }
    float4 o;
    o.x = gr + bhh[i]; o.y = gz + bhh[16 + i]; o.z = gn + bhh[32 + i]; o.w = m[i];
    *reinterpret_cast<float4*>(ghm + (size_t)c * 64 + i * 4) = o;
  }
  if (c < 6561) {
#pragma unroll
    for (int i = 0; i < 16; ++i) {
      float acc = 0.f;
#pragma unroll
      for (int j = 0; j < 16; ++j) acc = fmaf(act_w[i * 16 + j], m[j], acc);
      ytab[(size_t)c * 16 + i] = tanh_xla(acc + act_b[i]);
    }
  }
}

// ---------------- K4: the scan. 16 lanes per batch element ----------------
// Force-batched 16-way broadcast: 16 ds_bpermute_b32 issued back-to-back into
// 16 DISTINCT registers (early-clobber outputs), one lgkmcnt(0) wait. The
// compiler's register minimization had been serializing these (VGPR_Count=48:
// one temp reg -> wait after every bpermute -> ~2400cy/step exposed latency).
__device__ __forceinline__ void bperm16(int base4, float v, float* o) {
  asm volatile(
      "ds_bpermute_b32 %0, %16, %17 offset:0\n\t"
      "ds_bpermute_b32 %1, %16, %17 offset:4\n\t"
      "ds_bpermute_b32 %2, %16, %17 offset:8\n\t"
      "ds_bpermute_b32 %3, %16, %17 offset:12\n\t"
      "ds_bpermute_b32 %4, %16, %17 offset:16\n\t"
      "ds_bpermute_b32 %5, %16, %17 offset:20\n\t"
      "ds_bpermute_b32 %6, %16, %17 offset:24\n\t"
      "ds_bpermute_b32 %7, %16, %17 offset:28\n\t"
      "ds_bpermute_b32 %8, %16, %17 offset:32\n\t"
      "ds_bpermute_b32 %9, %16, %17 offset:36\n\t"
      "ds_bpermute_b32 %10, %16, %17 offset:40\n\t"
      "ds_bpermute_b32 %11, %16, %17 offset:44\n\t"
      "ds_bpermute_b32 %12, %16, %17 offset:48\n\t"
      "ds_bpermute_b32 %13, %16, %17 offset:52\n\t"
      "ds_bpermute_b32 %14, %16, %17 offset:56\n\t"
      "ds_bpermute_b32 %15, %16, %17 offset:60\n\t"
      "s_waitcnt lgkmcnt(0)"
      : "=&v"(o[0]), "=&v"(o[1]), "=&v"(o[2]), "=&v"(o[3]),
        "=&v"(o[4]), "=&v"(o[5]), "=&v"(o[6]), "=&v"(o[7]),
        "=&v"(o[8]), "=&v"(o[9]), "=&v"(o[10]), "=&v"(o[11]),
        "=&v"(o[12]), "=&v"(o[13]), "=&v"(o[14]), "=&v"(o[15])
      : "v"(base4), "v"(v));
}

// add the row_ror:<N>-moved copy of v (16-lane row rotation, VALU pipe)
#define DPP_ROR_ADD(v, CTRL)                                               \
  v += __int_as_float(__builtin_amdgcn_update_dpp(                         \
      0, __float_as_int(v), (CTRL), 0xF, 0xF, true))

__global__ __launch_bounds__(64, 1) void k_scan(
    const unsigned short* __restrict__ xcodes,
    const float* __restrict__ ghm,  // [6562][64]
    const float* __restrict__ gip,  // [6561][64]
    const float* __restrict__ m2q_w0, const float* __restrict__ m2q_b0,
    const float* __restrict__ m2q_w1, const float* __restrict__ m2q_b1,
    const float* __restrict__ m2q_w2, const float* __restrict__ m2q_b2,
    unsigned short* __restrict__ qcodes) {
  int lane = threadIdx.x & 15;
  int b = (blockIdx.x * 64 + threadIdx.x) >> 4;  // 0..2047
  int base4 = (threadIdx.x & 48) << 2;           // bpermute byte addr of group lane 0
  int lane16 = lane * 16;                        // byte offset of this lane's float4

  // per-lane m2q weight rows
  float w0r[16], w1r[16], w2r[16];
#pragma unroll
  for (int j = 0; j < 16; j += 4) {
    float4 a = *reinterpret_cast<const float4*>(m2q_w0 + lane * 16 + j);
    w0r[j] = a.x; w0r[j + 1] = a.y; w0r[j + 2] = a.z; w0r[j + 3] = a.w;
    float4 bq = *reinterpret_cast<const float4*>(m2q_w1 + lane * 16 + j);
    w1r[j] = bq.x; w1r[j + 1] = bq.y; w1r[j + 2] = bq.z; w1r[j + 3] = bq.w;
    float4 cq = *reinterpret_cast<const float4*>(m2q_w2 + (lane & 7) * 16 + j);
    w2r[j] = cq.x; w2r[j + 1] = cq.y; w2r[j + 2] = cq.z; w2r[j + 3] = cq.w;
  }
  float b0l = m2q_b0[lane], b1l = m2q_b1[lane], b2l = m2q_b2[lane & 7];
  // digit weight: 3^(lane&7) * 256 as float (exact); zero on lanes 8..15 so a
  // full 16-lane rotate-reduce counts each digit exactly once
  int p3i = 1;
  for (int k = 0; k < (lane & 7); ++k) p3i *= 3;
  float w3f = (lane < 8) ? (float)(p3i * 256) : 0.0f;
  const int kOffBias = 3280 * 256;  // sum of 3^k*256, k=0..7

  const char* ghmB = (const char*)ghm;
  const char* gipB = (const char*)gip;

  int qoff = 6561 * 256;  // byte offset of initial-state row
  unsigned xc = xcodes[b];
  float4 i4 = *reinterpret_cast<const float4*>(gipB + (unsigned)(((int)xc << 8) + lane16));

  for (int t = 0; t < T_DIM; ++t) {
    float4 g4 = *reinterpret_cast<const float4*>(ghmB + (unsigned)(qoff + lane16));
    // prefetch next step's GI row (independent of qprev chain)
    int tn = (t + 1 < T_DIM) ? t + 1 : T_DIM - 1;
    unsigned xcn = xcodes[tn * B_DIM + b];
    float4 i4n = *reinterpret_cast<const float4*>(gipB + (unsigned)(((int)xcn << 8) + lane16));

    float r = sigmoid_xla(i4.x + g4.x);
    float z = sigmoid_xla(i4.y + g4.y);
    float n = tanh_xla(fmaf(r, g4.z, i4.z));
    float h = (1.0f - z) * n + z * g4.w;

    // layer 0: one force-batched broadcast round, then the order-preserving
    // fma chain (identical arithmetic -> bit-exact)
    float hv[16];
    bperm16(base4, h, hv);
    float acc = 0.f;
#pragma unroll
    for (int j = 0; j < 16; ++j) acc = fmaf(w0r[j], hv[j], acc);
    float t0 = tanh_xla(acc + b0l);

    float tv0[16];
    bperm16(base4, t0, tv0);
    acc = 0.f;
#pragma unroll
    for (int j = 0; j < 16; ++j) acc = fmaf(w1r[j], tv0[j], acc);
    float t1 = tanh_xla(acc + b1l);

    float tv1[16];
    bperm16(base4, t1, tv1);
    acc = 0.f;
#pragma unroll
    for (int j = 0; j < 16; ++j) acc = fmaf(w2r[j], tv1[j], acc);

    // ternary digit as float, pre-scaled by 3^k*256 (exact integers in fp32)
    float s = acc + b2l;
    float soft = 1.5f * tanh_xla(s) + 0.5f * tanh_xla(-3.0f * s);
    float st = rintf(soft) * w3f;  // in {-1,0,1} * 3^k*256 (0 on lanes 8..15)
    // exact-integer all-reduce across the 16-lane row: 4 DPP rotate+add rounds
    DPP_ROR_ADD(st, 0x128);  // row_ror:8
    DPP_ROR_ADD(st, 0x124);  // row_ror:4
    DPP_ROR_ADD(st, 0x122);  // row_ror:2
    DPP_ROR_ADD(st, 0x121);  // row_ror:1
    qoff = (int)st + kOffBias;  // byte offset = qcode*256

    if (lane == 0) qcodes[t * B_DIM + b] = (unsigned short)((unsigned)qoff >> 8);
    i4 = i4n;
  }
}

// ---------------- K5: output gather out[e] = Y[qcode[e]] ----------------
__global__ __launch_bounds__(256) void k_out(
    const unsigned short* __restrict__ qcodes,
    const float* __restrict__ ytab,
    float* __restrict__ out) {
  int i = blockIdx.x * 256 + threadIdx.x;  // over NELEM*4 float4s, grid exact
  int e = i >> 2, sub = i & 3;
  unsigned c = qcodes[e];
  float4 y = *reinterpret_cast<const float4*>(ytab + (size_t)c * 16 + sub * 4);
  reinterpret_cast<float4*>(out)[i] = y;
}

extern "C" void kernel_launch(void* const* d_in, const int* in_sizes, int n_in,
                              void* d_out, int out_size, void* d_ws, size_t ws_size,
                              hipStream_t stream) {
  (void)in_sizes; (void)n_in; (void)out_size; (void)ws_size;
  const float* x       = (const float*)d_in[0];
  const float* obs_w0  = (const float*)d_in[1];
  const float* obs_b0  = (const float*)d_in[2];
  const float* obs_w1  = (const float*)d_in[3];
  const float* obs_b1  = (const float*)d_in[4];
  const float* obs_w2  = (const float*)d_in[5];
  const float* obs_b2  = (const float*)d_in[6];
  const float* gru_wih = (const float*)d_in[7];
  const float* gru_whh = (const float*)d_in[8];
  const float* gru_bih = (const float*)d_in[9];
  const float* gru_bhh = (const float*)d_in[10];
  const float* m2q_w0  = (const float*)d_in[11];
  const float* m2q_b0  = (const float*)d_in[12];
  const float* m2q_w1  = (const float*)d_in[13];
  const float* m2q_b1  = (const float*)d_in[14];
  const float* m2q_w2  = (const float*)d_in[15];
  const float* m2q_b2  = (const float*)d_in[16];
  const float* q2m_w0  = (const float*)d_in[17];
  const float* q2m_b0  = (const float*)d_in[18];
  const float* q2m_w1  = (const float*)d_in[19];
  const float* q2m_b1  = (const float*)d_in[20];
  const float* q2m_w2  = (const float*)d_in[21];
  const float* q2m_b2  = (const float*)d_in[22];
  const float* act_w   = (const float*)d_in[23];
  const float* act_b   = (const float*)d_in[24];

  char* ws = (char*)d_ws;
  unsigned short* xcodes = (unsigned short*)(ws);
  unsigned short* qcodes = (unsigned short*)(ws + (2u << 20));
  float* gip  = (float*)(ws + (4u << 20));
  float* ghm  = (float*)(ws + (6u << 20));
  float* ytab = (float*)(ws + (8u << 20));

  k_gi<<<26, 256, 0, stream>>>(gru_wih, gru_bih, gip);
  k_mtab<<<26, 256, 0, stream>>>(q2m_w0, q2m_b0, q2m_w1, q2m_b1, q2m_w2, q2m_b2,
                                 gru_whh, gru_bhh, act_w, act_b, ghm, ytab);
  k_obs<<<NELEM / 256, 256, 0, stream>>>(x, obs_w0, obs_b0, obs_w1, obs_b1,
                                         obs_w2, obs_b2, xcodes);
  k_scan<<<(B_DIM * 16) / 64, 64, 0, stream>>>(xcodes, ghm, gip,
                                               m2q_w0, m2q_b0, m2q_w1, m2q_b1,
                                               m2q_w2, m2q_b2, qcodes);
  k_out<<<(NELEM * 4) / 256, 256, 0, stream>>>(qcodes, ytab, (float*)d_out);
}

// Round 4
// 1097.744 us; speedup vs baseline: 1.0781x; 1.0022x over previous
//
#include <hip/hip_runtime.h>

// QBN_GRU_Base on MI355X.
// Ternary bottlenecks (dim 8) make the recurrence finite-state:
//   xq, q in {-1,0,1}^8 -> 6561 codes. Memoize
//     GI[code][64]   = xq@wih.T + bih            (packed [i*4+{r,z,n,pad}])
//     GHM[code][64]  = {m@whh.T + bhh, m}        (packed [i*4+{r,z,n,m}], row 6561 = h0 state)
//     Y[code][16]    = tanh(m@act_w.T + act_b)
// Scan step = 2 table-row loads + gates + m2q (640 MAC) across 16 lanes/elem.
// The scan's wall time is 512 x per-step dependent-chain latency (occupancy
// is irrelevant; each chain is serial). Ladder so far:
//   R2: VGPR=48, compiler serialized the 16 per-layer bpermutes  -> 664us
//   R3: bperm16 asm block (16 early-clobber outs, one lgkmcnt)   -> 591us
//       but VGPR=44: the 48 m2q weight floats are REMATERIALIZED from
//       memory inside the t-loop (legal for const __restrict__ loads),
//       ~1800cy/step of exposed L1/L2 latency on the dependent chain.
// R4 fix: launder every loop-invariant per-lane value (weights, biases,
// digit scale) through an empty asm identity ("+v") before the loop. The
// values become opaque -> rematerialization illegal -> RA must keep them
// in VGPRs (budget 512 via __launch_bounds__(64,1)). Zero extra
// instructions, bit-identical values -> absmax must stay 0.0.
// Numerics: XLA/Eigen rational tanh, logistic = 0.5+0.5*tanh(0.5x), fma
// dots in fixed j=0..15 order — identical float expressions throughout.

#define T_DIM 512
#define B_DIM 2048
#define NELEM (T_DIM * B_DIM)

__device__ __forceinline__ float tanh_xla(float x) {
  // Eigen/XLA generic_fast_tanh_float
  const float kClamp = 7.99881172180175781f;
  float xc = fminf(fmaxf(x, -kClamp), kClamp);
  float x2 = xc * xc;
  float p = fmaf(x2, -2.76076847742355e-16f, 2.00018790482477e-13f);
  p = fmaf(x2, p, -8.60467152213735e-11f);
  p = fmaf(x2, p, 5.12229709037114e-08f);
  p = fmaf(x2, p, 1.48572235717979e-05f);
  p = fmaf(x2, p, 6.37261928875436e-04f);
  p = fmaf(x2, p, 4.89352455891786e-03f);
  p = xc * p;
  float q = fmaf(x2, 1.19825839466702e-06f, 1.18534705686654e-04f);
  q = fmaf(x2, q, 2.26843463243900e-03f);
  q = fmaf(x2, q, 4.89352518554385e-03f);
  float r = p / q;
  return (fabsf(x) < 0.0004f) ? x : r;
}

__device__ __forceinline__ float sigmoid_xla(float x) {
  return 0.5f + 0.5f * tanh_xla(0.5f * x);
}

__device__ __forceinline__ int ternary_digit(float v) {
  float soft = 1.5f * tanh_xla(v) + 0.5f * tanh_xla(-3.0f * v);
  return (int)rintf(soft) + 1;
}

// ---------------- K1: obs encoder -> xcode[T*B] ----------------
__global__ __launch_bounds__(256) void k_obs(
    const float* __restrict__ x,
    const float* __restrict__ w0, const float* __restrict__ b0,
    const float* __restrict__ w1, const float* __restrict__ b1,
    const float* __restrict__ w2, const float* __restrict__ b2,
    unsigned short* __restrict__ xcodes) {
  int e = blockIdx.x * 256 + threadIdx.x;  // grid is exact
  const float* xr = x + (size_t)e * 64;
  float xv[64];
#pragma unroll
  for (int j = 0; j < 64; j += 4) {
    float4 v = *reinterpret_cast<const float4*>(xr + j);
    xv[j] = v.x; xv[j + 1] = v.y; xv[j + 2] = v.z; xv[j + 3] = v.w;
  }
  float h1[28];
#pragma unroll
  for (int k = 0; k < 28; ++k) {
    float acc = 0.0f;
#pragma unroll
    for (int j = 0; j < 64; ++j) acc = fmaf(w0[k * 64 + j], xv[j], acc);
    h1[k] = tanh_xla(acc + b0[k]);
  }
  float h2[28];
#pragma unroll
  for (int k = 0; k < 28; ++k) {
    float acc = 0.0f;
#pragma unroll
    for (int j = 0; j < 28; ++j) acc = fmaf(w1[k * 28 + j], h1[j], acc);
    h2[k] = tanh_xla(acc + b1[k]);
  }
  const int p3[8] = {1, 3, 9, 27, 81, 243, 729, 2187};
  unsigned code = 0;
#pragma unroll
  for (int k = 0; k < 8; ++k) {
    float acc = 0.0f;
#pragma unroll
    for (int j = 0; j < 28; ++j) acc = fmaf(w2[k * 28 + j], h2[j], acc);
    code += (unsigned)(ternary_digit(acc + b2[k]) * p3[k]);
  }
  xcodes[e] = (unsigned short)code;
}

// ---------------- K2: GI table [6561][64] ----------------
__global__ __launch_bounds__(256) void k_gi(
    const float* __restrict__ wih, const float* __restrict__ bih,
    float* __restrict__ gip) {
  int c = blockIdx.x * 256 + threadIdx.x;
  if (c >= 6561) return;
  float q[8];
  unsigned cc = (unsigned)c;
#pragma unroll
  for (int k = 0; k < 8; ++k) { q[k] = (float)((int)(cc % 3u) - 1); cc /= 3u; }
#pragma unroll
  for (int i = 0; i < 16; ++i) {
    float gr = 0.f, gz = 0.f, gn = 0.f;
#pragma unroll
    for (int j = 0; j < 8; ++j) {
      gr = fmaf(wih[i * 8 + j], q[j], gr);
      gz = fmaf(wih[(16 + i) * 8 + j], q[j], gz);
      gn = fmaf(wih[(32 + i) * 8 + j], q[j], gn);
    }
    float4 o;
    o.x = gr + bih[i]; o.y = gz + bih[16 + i]; o.z = gn + bih[32 + i]; o.w = 0.f;
    *reinterpret_cast<float4*>(gip + (size_t)c * 64 + i * 4) = o;
  }
}

// ---------------- K3: GHM [6562][64] + Y [6561][16] ----------------
__global__ __launch_bounds__(256) void k_mtab(
    const float* __restrict__ q2m_w0, const float* __restrict__ q2m_b0,
    const float* __restrict__ q2m_w1, const float* __restrict__ q2m_b1,
    const float* __restrict__ q2m_w2, const float* __restrict__ q2m_b2,
    const float* __restrict__ whh, const float* __restrict__ bhh,
    const float* __restrict__ act_w, const float* __restrict__ act_b,
    float* __restrict__ ghm, float* __restrict__ ytab) {
  int c = blockIdx.x * 256 + threadIdx.x;
  if (c > 6561) return;
  float m[16];
  if (c == 6561) {
#pragma unroll
    for (int i = 0; i < 16; ++i) m[i] = 0.0f;  // h0 = 0
  } else {
    float q[8];
    unsigned cc = (unsigned)c;
#pragma unroll
    for (int k = 0; k < 8; ++k) { q[k] = (float)((int)(cc % 3u) - 1); cc /= 3u; }
    float a[16];
#pragma unroll
    for (int i = 0; i < 16; ++i) {
      float acc = 0.f;
#pragma unroll
      for (int j = 0; j < 8; ++j) acc = fmaf(q2m_w0[i * 8 + j], q[j], acc);
      a[i] = tanh_xla(acc + q2m_b0[i]);
    }
    float d[16];
#pragma unroll
    for (int i = 0; i < 16; ++i) {
      float acc = 0.f;
#pragma unroll
      for (int j = 0; j < 16; ++j) acc = fmaf(q2m_w1[i * 16 + j], a[j], acc);
      d[i] = tanh_xla(acc + q2m_b1[i]);
    }
#pragma unroll
    for (int i = 0; i < 16; ++i) {
      float acc = 0.f;
#pragma unroll
      for (int j = 0; j < 16; ++j) acc = fmaf(q2m_w2[i * 16 + j], d[j], acc);
      m[i] = tanh_xla(acc + q2m_b2[i]);
    }
  }
#pragma unroll
  for (int i = 0; i < 16; ++i) {
    float gr = 0.f, gz = 0.f, gn = 0.f;
#pragma unroll
    for (int j = 0; j < 16; ++j) {
      gr = fmaf(whh[i * 16 + j], m[j], gr);
      gz = fmaf(whh[(16 + i) * 16 + j], m[j], gz);
      gn = fmaf(whh[(32 + i) * 16 + j], m[j], gn);
    }
    float4 o;
    o.x = gr + bhh[i]; o.y = gz + bhh[16 + i]; o.z = gn + bhh[32 + i]; o.w = m[i];
    *reinterpret_cast<float4*>(ghm + (size_t)c * 64 + i * 4) = o;
  }
  if (c < 6561) {
#pragma unroll
    for (int i = 0; i < 16; ++i) {
      float acc = 0.f;
#pragma unroll
      for (int j = 0; j < 16; ++j) acc = fmaf(act_w[i * 16 + j], m[j], acc);
      ytab[(size_t)c * 16 + i] = tanh_xla(acc + act_b[i]);
    }
  }
}

// ---------------- K4: the scan. 16 lanes per batch element ----------------
// Force-batched 16-way broadcast: 16 ds_bpermute_b32 issued back-to-back into
// 16 DISTINCT registers (early-clobber outputs), one lgkmcnt(0) wait.
__device__ __forceinline__ void bperm16(int base4, float v, float* o) {
  asm volatile(
      "ds_bpermute_b32 %0, %16, %17 offset:0\n\t"
      "ds_bpermute_b32 %1, %16, %17 offset:4\n\t"
      "ds_bpermute_b32 %2, %16, %17 offset:8\n\t"
      "ds_bpermute_b32 %3, %16, %17 offset:12\n\t"
      "ds_bpermute_b32 %4, %16, %17 offset:16\n\t"
      "ds_bpermute_b32 %5, %16, %17 offset:20\n\t"
      "ds_bpermute_b32 %6, %16, %17 offset:24\n\t"
      "ds_bpermute_b32 %7, %16, %17 offset:28\n\t"
      "ds_bpermute_b32 %8, %16, %17 offset:32\n\t"
      "ds_bpermute_b32 %9, %16, %17 offset:36\n\t"
      "ds_bpermute_b32 %10, %16, %17 offset:40\n\t"
      "ds_bpermute_b32 %11, %16, %17 offset:44\n\t"
      "ds_bpermute_b32 %12, %16, %17 offset:48\n\t"
      "ds_bpermute_b32 %13, %16, %17 offset:52\n\t"
      "ds_bpermute_b32 %14, %16, %17 offset:56\n\t"
      "ds_bpermute_b32 %15, %16, %17 offset:60\n\t"
      "s_waitcnt lgkmcnt(0)"
      : "=&v"(o[0]), "=&v"(o[1]), "=&v"(o[2]), "=&v"(o[3]),
        "=&v"(o[4]), "=&v"(o[5]), "=&v"(o[6]), "=&v"(o[7]),
        "=&v"(o[8]), "=&v"(o[9]), "=&v"(o[10]), "=&v"(o[11]),
        "=&v"(o[12]), "=&v"(o[13]), "=&v"(o[14]), "=&v"(o[15])
      : "v"(base4), "v"(v));
}

// opaque identity: makes a value un-rematerializable so RA keeps it resident
#define PIN_V(x) asm("" : "+v"(x))

// add the row_ror:<N>-moved copy of v (16-lane row rotation, VALU pipe)
#define DPP_ROR_ADD(v, CTRL)                                               \
  v += __int_as_float(__builtin_amdgcn_update_dpp(                         \
      0, __float_as_int(v), (CTRL), 0xF, 0xF, true))

__global__ __launch_bounds__(64, 1) void k_scan(
    const unsigned short* __restrict__ xcodes,
    const float* __restrict__ ghm,  // [6562][64]
    const float* __restrict__ gip,  // [6561][64]
    const float* __restrict__ m2q_w0, const float* __restrict__ m2q_b0,
    const float* __restrict__ m2q_w1, const float* __restrict__ m2q_b1,
    const float* __restrict__ m2q_w2, const float* __restrict__ m2q_b2,
    unsigned short* __restrict__ qcodes) {
  int lane = threadIdx.x & 15;
  int b = (blockIdx.x * 64 + threadIdx.x) >> 4;  // 0..2047
  int base4 = (threadIdx.x & 48) << 2;           // bpermute byte addr of group lane 0
  int lane16 = lane * 16;                        // byte offset of this lane's float4

  // per-lane m2q weight rows
  float w0r[16], w1r[16], w2r[16];
#pragma unroll
  for (int j = 0; j < 16; j += 4) {
    float4 a = *reinterpret_cast<const float4*>(m2q_w0 + lane * 16 + j);
    w0r[j] = a.x; w0r[j + 1] = a.y; w0r[j + 2] = a.z; w0r[j + 3] = a.w;
    float4 bq = *reinterpret_cast<const float4*>(m2q_w1 + lane * 16 + j);
    w1r[j] = bq.x; w1r[j + 1] = bq.y; w1r[j + 2] = bq.z; w1r[j + 3] = bq.w;
    float4 cq = *reinterpret_cast<const float4*>(m2q_w2 + (lane & 7) * 16 + j);
    w2r[j] = cq.x; w2r[j + 1] = cq.y; w2r[j + 2] = cq.z; w2r[j + 3] = cq.w;
  }
  float b0l = m2q_b0[lane], b1l = m2q_b1[lane], b2l = m2q_b2[lane & 7];
  // digit weight: 3^(lane&7) * 256 as float (exact); zero on lanes 8..15 so a
  // full 16-lane rotate-reduce counts each digit exactly once
  int p3i = 1;
  for (int k = 0; k < (lane & 7); ++k) p3i *= 3;
  float w3f = (lane < 8) ? (float)(p3i * 256) : 0.0f;
  const int kOffBias = 3280 * 256;  // sum of 3^k*256, k=0..7

  // R4: launder all loop-invariant per-lane values through an opaque asm
  // identity. const-__restrict__ loads are otherwise legally rematerialized
  // INSIDE the t-loop by the register allocator (R3 counters: VGPR=44 with 48
  // live weights impossible), putting ~1800cy/step of L1/L2 latency on the
  // serial chain. Opaque values cannot be recomputed -> must stay in VGPRs.
#pragma unroll
  for (int j = 0; j < 16; ++j) {
    PIN_V(w0r[j]); PIN_V(w1r[j]); PIN_V(w2r[j]);
  }
  PIN_V(b0l); PIN_V(b1l); PIN_V(b2l); PIN_V(w3f);

  const char* ghmB = (const char*)ghm;
  const char* gipB = (const char*)gip;

  int qoff = 6561 * 256;  // byte offset of initial-state row
  unsigned xc = xcodes[b];
  float4 i4 = *reinterpret_cast<const float4*>(gipB + (unsigned)(((int)xc << 8) + lane16));

  for (int t = 0; t < T_DIM; ++t) {
    float4 g4 = *reinterpret_cast<const float4*>(ghmB + (unsigned)(qoff + lane16));
    // prefetch next step's GI row (independent of qprev chain)
    int tn = (t + 1 < T_DIM) ? t + 1 : T_DIM - 1;
    unsigned xcn = xcodes[tn * B_DIM + b];
    float4 i4n = *reinterpret_cast<const float4*>(gipB + (unsigned)(((int)xcn << 8) + lane16));

    float r = sigmoid_xla(i4.x + g4.x);
    float z = sigmoid_xla(i4.y + g4.y);
    float n = tanh_xla(fmaf(r, g4.z, i4.z));
    float h = (1.0f - z) * n + z * g4.w;

    // layer 0: one force-batched broadcast round, then the order-preserving
    // fma chain (identical arithmetic -> bit-exact)
    float hv[16];
    bperm16(base4, h, hv);
    float acc = 0.f;
#pragma unroll
    for (int j = 0; j < 16; ++j) acc = fmaf(w0r[j], hv[j], acc);
    float t0 = tanh_xla(acc + b0l);

    float tv0[16];
    bperm16(base4, t0, tv0);
    acc = 0.f;
#pragma unroll
    for (int j = 0; j < 16; ++j) acc = fmaf(w1r[j], tv0[j], acc);
    float t1 = tanh_xla(acc + b1l);

    float tv1[16];
    bperm16(base4, t1, tv1);
    acc = 0.f;
#pragma unroll
    for (int j = 0; j < 16; ++j) acc = fmaf(w2r[j], tv1[j], acc);

    // ternary digit as float, pre-scaled by 3^k*256 (exact integers in fp32)
    float s = acc + b2l;
    float soft = 1.5f * tanh_xla(s) + 0.5f * tanh_xla(-3.0f * s);
    float st = rintf(soft) * w3f;  // in {-1,0,1} * 3^k*256 (0 on lanes 8..15)
    // exact-integer all-reduce across the 16-lane row: 4 DPP rotate+add rounds
    DPP_ROR_ADD(st, 0x128);  // row_ror:8
    DPP_ROR_ADD(st, 0x124);  // row_ror:4
    DPP_ROR_ADD(st, 0x122);  // row_ror:2
    DPP_ROR_ADD(st, 0x121);  // row_ror:1
    qoff = (int)st + kOffBias;  // byte offset = qcode*256

    if (lane == 0) qcodes[t * B_DIM + b] = (unsigned short)((unsigned)qoff >> 8);
    i4 = i4n;
  }
}

// ---------------- K5: output gather out[e] = Y[qcode[e]] ----------------
__global__ __launch_bounds__(256) void k_out(
    const unsigned short* __restrict__ qcodes,
    const float* __restrict__ ytab,
    float* __restrict__ out) {
  int i = blockIdx.x * 256 + threadIdx.x;  // over NELEM*4 float4s, grid exact
  int e = i >> 2, sub = i & 3;
  unsigned c = qcodes[e];
  float4 y = *reinterpret_cast<const float4*>(ytab + (size_t)c * 16 + sub * 4);
  reinterpret_cast<float4*>(out)[i] = y;
}

extern "C" void kernel_launch(void* const* d_in, const int* in_sizes, int n_in,
                              void* d_out, int out_size, void* d_ws, size_t ws_size,
                              hipStream_t stream) {
  (void)in_sizes; (void)n_in; (void)out_size; (void)ws_size;
  const float* x       = (const float*)d_in[0];
  const float* obs_w0  = (const float*)d_in[1];
  const float* obs_b0  = (const float*)d_in[2];
  const float* obs_w1  = (const float*)d_in[3];
  const float* obs_b1  = (const float*)d_in[4];
  const float* obs_w2  = (const float*)d_in[5];
  const float* obs_b2  = (const float*)d_in[6];
  const float* gru_wih = (const float*)d_in[7];
  const float* gru_whh = (const float*)d_in[8];
  const float* gru_bih = (const float*)d_in[9];
  const float* gru_bhh = (const float*)d_in[10];
  const float* m2q_w0  = (const float*)d_in[11];
  const float* m2q_b0  = (const float*)d_in[12];
  const float* m2q_w1  = (const float*)d_in[13];
  const float* m2q_b1  = (const float*)d_in[14];
  const float* m2q_w2  = (const float*)d_in[15];
  const float* m2q_b2  = (const float*)d_in[16];
  const float* q2m_w0  = (const float*)d_in[17];
  const float* q2m_b0  = (const float*)d_in[18];
  const float* q2m_w1  = (const float*)d_in[19];
  const float* q2m_b1  = (const float*)d_in[20];
  const float* q2m_w2  = (const float*)d_in[21];
  const float* q2m_b2  = (const float*)d_in[22];
  const float* act_w   = (const float*)d_in[23];
  const float* act_b   = (const float*)d_in[24];

  char* ws = (char*)d_ws;
  unsigned short* xcodes = (unsigned short*)(ws);
  unsigned short* qcodes = (unsigned short*)(ws + (2u << 20));
  float* gip  = (float*)(ws + (4u << 20));
  float* ghm  = (float*)(ws + (6u << 20));
  float* ytab = (float*)(ws + (8u << 20));

  k_gi<<<26, 256, 0, stream>>>(gru_wih, gru_bih, gip);
  k_mtab<<<26, 256, 0, stream>>>(q2m_w0, q2m_b0, q2m_w1, q2m_b1, q2m_w2, q2m_b2,
                                 gru_whh, gru_bhh, act_w, act_b, ghm, ytab);
  k_obs<<<NELEM / 256, 256, 0, stream>>>(x, obs_w0, obs_b0, obs_w1, obs_b1,
                                         obs_w2, obs_b2, xcodes);
  k_scan<<<(B_DIM * 16) / 64, 64, 0, stream>>>(xcodes, ghm, gip,
                                               m2q_w0, m2q_b0, m2q_w1, m2q_b1,
                                               m2q_w2, m2q_b2, qcodes);
  k_out<<<(NELEM * 4) / 256, 256, 0, stream>>>(qcodes, ytab, (float*)d_out);
}

// Round 5
// 1054.106 us; speedup vs baseline: 1.1228x; 1.0414x over previous
//
#include <hip/hip_runtime.h>

// QBN_GRU_Base on MI355X.
// Ternary bottlenecks (dim 8) make the recurrence finite-state:
//   xq, q in {-1,0,1}^8 -> 6561 codes. Memoize
//     GI[code][64]   = xq@wih.T + bih            (packed [i*4+{r,z,n,pad}])
//     GHM[code][64]  = {m@whh.T + bhh, m}        (packed [i*4+{r,z,n,m}], row 6561 = h0 state)
//     Y[code][16]    = tanh(m@act_w.T + act_b)
// Scan step = 2 table-row loads + gates + m2q (640 MAC) across 16 lanes/elem.
// The scan's wall time is 512 x per-step dependent-chain latency (occupancy
// is irrelevant; each chain is serial). Ladder:
//   R2: compiler serialized the 16 per-layer bpermutes (VGPR=48)  -> 664us
//   R3: bperm16 asm block (16 early-clobber outs, one lgkmcnt)    -> 591us
//   R4: non-volatile asm pins on weights: DEFEATED (VGPR stayed 44;
//       pure asm identities + their feeding loads were sunk into the
//       loop) -> 586us. Weights still reloaded on the serial chain.
// R5 fix (same theory, enforceable mechanics):
//   a) amdgpu_waves_per_eu(1,1): cap the scheduler's occupancy TARGET at
//      1 wave/EU. launch_bounds' 2nd arg only sets the minimum (a VGPR
//      ceiling); the scheduler still remat'd loads to shrink pressure to
//      44 regs chasing occupancy the 512-wave grid can never use.
//   b) in-loop VOLATILE pins: asm volatile("" : "+v"(w)) each iteration
//      makes every weight a loop-carried value defined by an opaque op ->
//      remat illegal, must stay in a VGPR. Zero instructions emitted.
// Numerics: XLA/Eigen rational tanh, logistic = 0.5+0.5*tanh(0.5x), fma
// dots in fixed j=0..15 order — identical float expressions throughout.

#define T_DIM 512
#define B_DIM 2048
#define NELEM (T_DIM * B_DIM)

__device__ __forceinline__ float tanh_xla(float x) {
  // Eigen/XLA generic_fast_tanh_float
  const float kClamp = 7.99881172180175781f;
  float xc = fminf(fmaxf(x, -kClamp), kClamp);
  float x2 = xc * xc;
  float p = fmaf(x2, -2.76076847742355e-16f, 2.00018790482477e-13f);
  p = fmaf(x2, p, -8.60467152213735e-11f);
  p = fmaf(x2, p, 5.12229709037114e-08f);
  p = fmaf(x2, p, 1.48572235717979e-05f);
  p = fmaf(x2, p, 6.37261928875436e-04f);
  p = fmaf(x2, p, 4.89352455891786e-03f);
  p = xc * p;
  float q = fmaf(x2, 1.19825839466702e-06f, 1.18534705686654e-04f);
  q = fmaf(x2, q, 2.26843463243900e-03f);
  q = fmaf(x2, q, 4.89352518554385e-03f);
  float r = p / q;
  return (fabsf(x) < 0.0004f) ? x : r;
}

__device__ __forceinline__ float sigmoid_xla(float x) {
  return 0.5f + 0.5f * tanh_xla(0.5f * x);
}

__device__ __forceinline__ int ternary_digit(float v) {
  float soft = 1.5f * tanh_xla(v) + 0.5f * tanh_xla(-3.0f * v);
  return (int)rintf(soft) + 1;
}

// ---------------- K1: obs encoder -> xcode[T*B] ----------------
__global__ __launch_bounds__(256) void k_obs(
    const float* __restrict__ x,
    const float* __restrict__ w0, const float* __restrict__ b0,
    const float* __restrict__ w1, const float* __restrict__ b1,
    const float* __restrict__ w2, const float* __restrict__ b2,
    unsigned short* __restrict__ xcodes) {
  int e = blockIdx.x * 256 + threadIdx.x;  // grid is exact
  const float* xr = x + (size_t)e * 64;
  float xv[64];
#pragma unroll
  for (int j = 0; j < 64; j += 4) {
    float4 v = *reinterpret_cast<const float4*>(xr + j);
    xv[j] = v.x; xv[j + 1] = v.y; xv[j + 2] = v.z; xv[j + 3] = v.w;
  }
  float h1[28];
#pragma unroll
  for (int k = 0; k < 28; ++k) {
    float acc = 0.0f;
#pragma unroll
    for (int j = 0; j < 64; ++j) acc = fmaf(w0[k * 64 + j], xv[j], acc);
    h1[k] = tanh_xla(acc + b0[k]);
  }
  float h2[28];
#pragma unroll
  for (int k = 0; k < 28; ++k) {
    float acc = 0.0f;
#pragma unroll
    for (int j = 0; j < 28; ++j) acc = fmaf(w1[k * 28 + j], h1[j], acc);
    h2[k] = tanh_xla(acc + b1[k]);
  }
  const int p3[8] = {1, 3, 9, 27, 81, 243, 729, 2187};
  unsigned code = 0;
#pragma unroll
  for (int k = 0; k < 8; ++k) {
    float acc = 0.0f;
#pragma unroll
    for (int j = 0; j < 28; ++j) acc = fmaf(w2[k * 28 + j], h2[j], acc);
    code += (unsigned)(ternary_digit(acc + b2[k]) * p3[k]);
  }
  xcodes[e] = (unsigned short)code;
}

// ---------------- K2: GI table [6561][64] ----------------
__global__ __launch_bounds__(256) void k_gi(
    const float* __restrict__ wih, const float* __restrict__ bih,
    float* __restrict__ gip) {
  int c = blockIdx.x * 256 + threadIdx.x;
  if (c >= 6561) return;
  float q[8];
  unsigned cc = (unsigned)c;
#pragma unroll
  for (int k = 0; k < 8; ++k) { q[k] = (float)((int)(cc % 3u) - 1); cc /= 3u; }
#pragma unroll
  for (int i = 0; i < 16; ++i) {
    float gr = 0.f, gz = 0.f, gn = 0.f;
#pragma unroll
    for (int j = 0; j < 8; ++j) {
      gr = fmaf(wih[i * 8 + j], q[j], gr);
      gz = fmaf(wih[(16 + i) * 8 + j], q[j], gz);
      gn = fmaf(wih[(32 + i) * 8 + j], q[j], gn);
    }
    float4 o;
    o.x = gr + bih[i]; o.y = gz + bih[16 + i]; o.z = gn + bih[32 + i]; o.w = 0.f;
    *reinterpret_cast<float4*>(gip + (size_t)c * 64 + i * 4) = o;
  }
}

// ---------------- K3: GHM [6562][64] + Y [6561][16] ----------------
__global__ __launch_bounds__(256) void k_mtab(
    const float* __restrict__ q2m_w0, const float* __restrict__ q2m_b0,
    const float* __restrict__ q2m_w1, const float* __restrict__ q2m_b1,
    const float* __restrict__ q2m_w2, const float* __restrict__ q2m_b2,
    const float* __restrict__ whh, const float* __restrict__ bhh,
    const float* __restrict__ act_w, const float* __restrict__ act_b,
    float* __restrict__ ghm, float* __restrict__ ytab) {
  int c = blockIdx.x * 256 + threadIdx.x;
  if (c > 6561) return;
  float m[16];
  if (c == 6561) {
#pragma unroll
    for (int i = 0; i < 16; ++i) m[i] = 0.0f;  // h0 = 0
  } else {
    float q[8];
    unsigned cc = (unsigned)c;
#pragma unroll
    for (int k = 0; k < 8; ++k) { q[k] = (float)((int)(cc % 3u) - 1); cc /= 3u; }
    float a[16];
#pragma unroll
    for (int i = 0; i < 16; ++i) {
      float acc = 0.f;
#pragma unroll
      for (int j = 0; j < 8; ++j) acc = fmaf(q2m_w0[i * 8 + j], q[j], acc);
      a[i] = tanh_xla(acc + q2m_b0[i]);
    }
    float d[16];
#pragma unroll
    for (int i = 0; i < 16; ++i) {
      float acc = 0.f;
#pragma unroll
      for (int j = 0; j < 16; ++j) acc = fmaf(q2m_w1[i * 16 + j], a[j], acc);
      d[i] = tanh_xla(acc + q2m_b1[i]);
    }
#pragma unroll
    for (int i = 0; i < 16; ++i) {
      float acc = 0.f;
#pragma unroll
      for (int j = 0; j < 16; ++j) acc = fmaf(q2m_w2[i * 16 + j], d[j], acc);
      m[i] = tanh_xla(acc + q2m_b2[i]);
    }
  }
#pragma unroll
  for (int i = 0; i < 16; ++i) {
    float gr = 0.f, gz = 0.f, gn = 0.f;
#pragma unroll
    for (int j = 0; j < 16; ++j) {
      gr = fmaf(whh[i * 16 + j], m[j], gr);
      gz = fmaf(whh[(16 + i) * 16 + j], m[j], gz);
      gn = fmaf(whh[(32 + i) * 16 + j], m[j], gn);
    }
    float4 o;
    o.x = gr + bhh[i]; o.y = gz + bhh[16 + i]; o.z = gn + bhh[32 + i]; o.w = m[i];
    *reinterpret_cast<float4*>(ghm + (size_t)c * 64 + i * 4) = o;
  }
  if (c < 6561) {
#pragma unroll
    for (int i = 0; i < 16; ++i) {
      float acc = 0.f;
#pragma unroll
      for (int j = 0; j < 16; ++j) acc = fmaf(act_w[i * 16 + j], m[j], acc);
      ytab[(size_t)c * 16 + i] = tanh_xla(acc + act_b[i]);
    }
  }
}

// ---------------- K4: the scan. 16 lanes per batch element ----------------
// Force-batched 16-way broadcast: 16 ds_bpermute_b32 issued back-to-back into
// 16 DISTINCT registers (early-clobber outputs), one lgkmcnt(0) wait.
__device__ __forceinline__ void bperm16(int base4, float v, float* o) {
  asm volatile(
      "ds_bpermute_b32 %0, %16, %17 offset:0\n\t"
      "ds_bpermute_b32 %1, %16, %17 offset:4\n\t"
      "ds_bpermute_b32 %2, %16, %17 offset:8\n\t"
      "ds_bpermute_b32 %3, %16, %17 offset:12\n\t"
      "ds_bpermute_b32 %4, %16, %17 offset:16\n\t"
      "ds_bpermute_b32 %5, %16, %17 offset:20\n\t"
      "ds_bpermute_b32 %6, %16, %17 offset:24\n\t"
      "ds_bpermute_b32 %7, %16, %17 offset:28\n\t"
      "ds_bpermute_b32 %8, %16, %17 offset:32\n\t"
      "ds_bpermute_b32 %9, %16, %17 offset:36\n\t"
      "ds_bpermute_b32 %10, %16, %17 offset:40\n\t"
      "ds_bpermute_b32 %11, %16, %17 offset:44\n\t"
      "ds_bpermute_b32 %12, %16, %17 offset:48\n\t"
      "ds_bpermute_b32 %13, %16, %17 offset:52\n\t"
      "ds_bpermute_b32 %14, %16, %17 offset:56\n\t"
      "ds_bpermute_b32 %15, %16, %17 offset:60\n\t"
      "s_waitcnt lgkmcnt(0)"
      : "=&v"(o[0]), "=&v"(o[1]), "=&v"(o[2]), "=&v"(o[3]),
        "=&v"(o[4]), "=&v"(o[5]), "=&v"(o[6]), "=&v"(o[7]),
        "=&v"(o[8]), "=&v"(o[9]), "=&v"(o[10]), "=&v"(o[11]),
        "=&v"(o[12]), "=&v"(o[13]), "=&v"(o[14]), "=&v"(o[15])
      : "v"(base4), "v"(v));
}

// loop-carried opaque identity (VOLATILE: cannot be sunk/duplicated/remat'd).
// Applied inside the loop, it makes the value loop-carried through an opaque
// op -> the register allocator MUST keep it resident in a VGPR.
#define PIN8(a, b, c, d, e, f, g, h)                                        \
  asm volatile("" : "+v"(a), "+v"(b), "+v"(c), "+v"(d), "+v"(e), "+v"(f),   \
                    "+v"(g), "+v"(h))

// add the row_ror:<N>-moved copy of v (16-lane row rotation, VALU pipe)
#define DPP_ROR_ADD(v, CTRL)                                               \
  v += __int_as_float(__builtin_amdgcn_update_dpp(                         \
      0, __float_as_int(v), (CTRL), 0xF, 0xF, true))

__global__ __launch_bounds__(64)
__attribute__((amdgpu_waves_per_eu(1, 1)))  // cap scheduler occupancy target:
                                            // stop pressure-motivated remat
void k_scan(
    const unsigned short* __restrict__ xcodes,
    const float* __restrict__ ghm,  // [6562][64]
    const float* __restrict__ gip,  // [6561][64]
    const float* __restrict__ m2q_w0, const float* __restrict__ m2q_b0,
    const float* __restrict__ m2q_w1, const float* __restrict__ m2q_b1,
    const float* __restrict__ m2q_w2, const float* __restrict__ m2q_b2,
    unsigned short* __restrict__ qcodes) {
  int lane = threadIdx.x & 15;
  int b = (blockIdx.x * 64 + threadIdx.x) >> 4;  // 0..2047
  int base4 = (threadIdx.x & 48) << 2;           // bpermute byte addr of group lane 0
  int lane16 = lane * 16;                        // byte offset of this lane's float4

  // per-lane m2q weight rows
  float w0r[16], w1r[16], w2r[16];
#pragma unroll
  for (int j = 0; j < 16; j += 4) {
    float4 a = *reinterpret_cast<const float4*>(m2q_w0 + lane * 16 + j);
    w0r[j] = a.x; w0r[j + 1] = a.y; w0r[j + 2] = a.z; w0r[j + 3] = a.w;
    float4 bq = *reinterpret_cast<const float4*>(m2q_w1 + lane * 16 + j);
    w1r[j] = bq.x; w1r[j + 1] = bq.y; w1r[j + 2] = bq.z; w1r[j + 3] = bq.w;
    float4 cq = *reinterpret_cast<const float4*>(m2q_w2 + (lane & 7) * 16 + j);
    w2r[j] = cq.x; w2r[j + 1] = cq.y; w2r[j + 2] = cq.z; w2r[j + 3] = cq.w;
  }
  float b0l = m2q_b0[lane], b1l = m2q_b1[lane], b2l = m2q_b2[lane & 7];
  // digit weight: 3^(lane&7) * 256 as float (exact); zero on lanes 8..15 so a
  // full 16-lane rotate-reduce counts each digit exactly once
  int p3i = 1;
  for (int k = 0; k < (lane & 7); ++k) p3i *= 3;
  float w3f = (lane < 8) ? (float)(p3i * 256) : 0.0f;
  const int kOffBias = 3280 * 256;  // sum of 3^k*256, k=0..7

  const char* ghmB = (const char*)ghm;
  const char* gipB = (const char*)gip;

  int qoff = 6561 * 256;  // byte offset of initial-state row
  unsigned xc = xcodes[b];
  float4 i4 = *reinterpret_cast<const float4*>(gipB + (unsigned)(((int)xc << 8) + lane16));

  for (int t = 0; t < T_DIM; ++t) {
    // R5: loop-carried volatile pins. Each weight/bias value is routed
    // through an opaque no-op EVERY iteration -> rematerializing the load
    // inside the loop is illegal; the 52 floats must stay in VGPRs
    // (budget 512 at 1 wave/EU). Emits zero instructions.
    PIN8(w0r[0], w0r[1], w0r[2], w0r[3], w0r[4], w0r[5], w0r[6], w0r[7]);
    PIN8(w0r[8], w0r[9], w0r[10], w0r[11], w0r[12], w0r[13], w0r[14], w0r[15]);
    PIN8(w1r[0], w1r[1], w1r[2], w1r[3], w1r[4], w1r[5], w1r[6], w1r[7]);
    PIN8(w1r[8], w1r[9], w1r[10], w1r[11], w1r[12], w1r[13], w1r[14], w1r[15]);
    PIN8(w2r[0], w2r[1], w2r[2], w2r[3], w2r[4], w2r[5], w2r[6], w2r[7]);
    PIN8(w2r[8], w2r[9], w2r[10], w2r[11], w2r[12], w2r[13], w2r[14], w2r[15]);
    asm volatile("" : "+v"(b0l), "+v"(b1l), "+v"(b2l), "+v"(w3f));

    float4 g4 = *reinterpret_cast<const float4*>(ghmB + (unsigned)(qoff + lane16));
    // prefetch next step's GI row (independent of qprev chain)
    int tn = (t + 1 < T_DIM) ? t + 1 : T_DIM - 1;
    unsigned xcn = xcodes[tn * B_DIM + b];
    float4 i4n = *reinterpret_cast<const float4*>(gipB + (unsigned)(((int)xcn << 8) + lane16));

    float r = sigmoid_xla(i4.x + g4.x);
    float z = sigmoid_xla(i4.y + g4.y);
    float n = tanh_xla(fmaf(r, g4.z, i4.z));
    float h = (1.0f - z) * n + z * g4.w;

    // layer 0: one force-batched broadcast round, then the order-preserving
    // fma chain (identical arithmetic -> bit-exact)
    float hv[16];
    bperm16(base4, h, hv);
    float acc = 0.f;
#pragma unroll
    for (int j = 0; j < 16; ++j) acc = fmaf(w0r[j], hv[j], acc);
    float t0 = tanh_xla(acc + b0l);

    float tv0[16];
    bperm16(base4, t0, tv0);
    acc = 0.f;
#pragma unroll
    for (int j = 0; j < 16; ++j) acc = fmaf(w1r[j], tv0[j], acc);
    float t1 = tanh_xla(acc + b1l);

    float tv1[16];
    bperm16(base4, t1, tv1);
    acc = 0.f;
#pragma unroll
    for (int j = 0; j < 16; ++j) acc = fmaf(w2r[j], tv1[j], acc);

    // ternary digit as float, pre-scaled by 3^k*256 (exact integers in fp32)
    float s = acc + b2l;
    float soft = 1.5f * tanh_xla(s) + 0.5f * tanh_xla(-3.0f * s);
    float st = rintf(soft) * w3f;  // in {-1,0,1} * 3^k*256 (0 on lanes 8..15)
    // exact-integer all-reduce across the 16-lane row: 4 DPP rotate+add rounds
    DPP_ROR_ADD(st, 0x128);  // row_ror:8
    DPP_ROR_ADD(st, 0x124);  // row_ror:4
    DPP_ROR_ADD(st, 0x122);  // row_ror:2
    DPP_ROR_ADD(st, 0x121);  // row_ror:1
    qoff = (int)st + kOffBias;  // byte offset = qcode*256

    if (lane == 0) qcodes[t * B_DIM + b] = (unsigned short)((unsigned)qoff >> 8);
    i4 = i4n;
  }
}

// ---------------- K5: output gather out[e] = Y[qcode[e]] ----------------
__global__ __launch_bounds__(256) void k_out(
    const unsigned short* __restrict__ qcodes,
    const float* __restrict__ ytab,
    float* __restrict__ out) {
  int i = blockIdx.x * 256 + threadIdx.x;  // over NELEM*4 float4s, grid exact
  int e = i >> 2, sub = i & 3;
  unsigned c = qcodes[e];
  float4 y = *reinterpret_cast<const float4*>(ytab + (size_t)c * 16 + sub * 4);
  reinterpret_cast<float4*>(out)[i] = y;
}

extern "C" void kernel_launch(void* const* d_in, const int* in_sizes, int n_in,
                              void* d_out, int out_size, void* d_ws, size_t ws_size,
                              hipStream_t stream) {
  (void)in_sizes; (void)n_in; (void)out_size; (void)ws_size;
  const float* x       = (const float*)d_in[0];
  const float* obs_w0  = (const float*)d_in[1];
  const float* obs_b0  = (const float*)d_in[2];
  const float* obs_w1  = (const float*)d_in[3];
  const float* obs_b1  = (const float*)d_in[4];
  const float* obs_w2  = (const float*)d_in[5];
  const float* obs_b2  = (const float*)d_in[6];
  const float* gru_wih = (const float*)d_in[7];
  const float* gru_whh = (const float*)d_in[8];
  const float* gru_bih = (const float*)d_in[9];
  const float* gru_bhh = (const float*)d_in[10];
  const float* m2q_w0  = (const float*)d_in[11];
  const float* m2q_b0  = (const float*)d_in[12];
  const float* m2q_w1  = (const float*)d_in[13];
  const float* m2q_b1  = (const float*)d_in[14];
  const float* m2q_w2  = (const float*)d_in[15];
  const float* m2q_b2  = (const float*)d_in[16];
  const float* q2m_w0  = (const float*)d_in[17];
  const float* q2m_b0  = (const float*)d_in[18];
  const float* q2m_w1  = (const float*)d_in[19];
  const float* q2m_b1  = (const float*)d_in[20];
  const float* q2m_w2  = (const float*)d_in[21];
  const float* q2m_b2  = (const float*)d_in[22];
  const float* act_w   = (const float*)d_in[23];
  const float* act_b   = (const float*)d_in[24];

  char* ws = (char*)d_ws;
  unsigned short* xcodes = (unsigned short*)(ws);
  unsigned short* qcodes = (unsigned short*)(ws + (2u << 20));
  float* gip  = (float*)(ws + (4u << 20));
  float* ghm  = (float*)(ws + (6u << 20));
  float* ytab = (float*)(ws + (8u << 20));

  k_gi<<<26, 256, 0, stream>>>(gru_wih, gru_bih, gip);
  k_mtab<<<26, 256, 0, stream>>>(q2m_w0, q2m_b0, q2m_w1, q2m_b1, q2m_w2, q2m_b2,
                                 gru_whh, gru_bhh, act_w, act_b, ghm, ytab);
  k_obs<<<NELEM / 256, 256, 0, stream>>>(x, obs_w0, obs_b0, obs_w1, obs_b1,
                                         obs_w2, obs_b2, xcodes);
  k_scan<<<(B_DIM * 16) / 64, 64, 0, stream>>>(xcodes, ghm, gip,
                                               m2q_w0, m2q_b0, m2q_w1, m2q_b1,
                                               m2q_w2, m2q_b2, qcodes);
  k_out<<<(NELEM * 4) / 256, 256, 0, stream>>>(qcodes, ytab, (float*)d_out);
}

// Round 7
// 1045.670 us; speedup vs baseline: 1.1318x; 1.0081x over previous
//
#include <hip/hip_runtime.h>

// QBN_GRU_Base on MI355X.
// Ternary bottlenecks (dim 8) make the recurrence finite-state:
//   xq, q in {-1,0,1}^8 -> 6561 codes. Memoize
//     GI[code][64]   = xq@wih.T + bih            (packed [i*4+{r,z,n,pad}])
//     GHM[code][64]  = {m@whh.T + bhh, m}        (packed [i*4+{r,z,n,m}], row 6561 = h0 state)
//     Y[code][16]    = tanh(m@act_w.T + act_b)
// Scan step = 2 table-row loads + gates + m2q (640 MAC) across 16 lanes/elem.
// Wall time of the scan = 512 x per-step dependent-chain latency. Ladder:
//   R2: compiler serialized the 16 per-layer bpermutes (VGPR=48)  -> 664us
//   R3: bperm16 asm block (16 early-clobber outs, one lgkmcnt)    -> 591us
//   R4: non-volatile weight pins: DEFEATED (sunk into loop)       -> 586us
//   R5: waves_per_eu(1,1) + in-loop volatile pins: VGPR 44->132   -> 549us
// R6/R7 changes (R7 = R6 resubmitted after infra failure; thr buffer moved
// from ws+10MB to ws+8.5MB to stay inside the proven <9MB ws footprint):
//   a) digit via thresholds: rintf(soft(s)) is a monotone step of s and
//      soft is exactly odd in float -> digit = (s>=th)-(s<=-th) with th
//      found by a 1-thread device binary search (k_thr). EXACTNESS: if any
//      lane is within 1e-3 of +-th (covers ULP-scale jitter; ~3% of steps)
//      the whole wave recomputes the exact rintf(soft) path. Removes the
//      2-tanh digit pair (~90-150cy incl. a full IEEE divide) from the
//      serial chain.
//   b) pins moved OUT of the loop but kept VOLATILE (cannot be sunk or
//      duplicated, unlike R4's pure asm) -> residency holds without 7
//      scheduler-barrier asms in the body.
//   c) tn = (t+1)&511 (branchless; last-step prefetch value is unused).
//   d) k_obs: amdgpu_waves_per_eu(1,4) to eliminate any spill pressure
//      from its ~110-float live set (xv[64]+h1[28]+h2 partials).
// Numerics: XLA/Eigen rational tanh, logistic = 0.5+0.5*tanh(0.5x), fma
// dots in fixed j=0..15 order — identical float expressions throughout.

#define T_DIM 512
#define B_DIM 2048
#define NELEM (T_DIM * B_DIM)

__device__ __forceinline__ float tanh_xla(float x) {
  // Eigen/XLA generic_fast_tanh_float
  const float kClamp = 7.99881172180175781f;
  float xc = fminf(fmaxf(x, -kClamp), kClamp);
  float x2 = xc * xc;
  float p = fmaf(x2, -2.76076847742355e-16f, 2.00018790482477e-13f);
  p = fmaf(x2, p, -8.60467152213735e-11f);
  p = fmaf(x2, p, 5.12229709037114e-08f);
  p = fmaf(x2, p, 1.48572235717979e-05f);
  p = fmaf(x2, p, 6.37261928875436e-04f);
  p = fmaf(x2, p, 4.89352455891786e-03f);
  p = xc * p;
  float q = fmaf(x2, 1.19825839466702e-06f, 1.18534705686654e-04f);
  q = fmaf(x2, q, 2.26843463243900e-03f);
  q = fmaf(x2, q, 4.89352518554385e-03f);
  float r = p / q;
  return (fabsf(x) < 0.0004f) ? x : r;
}

__device__ __forceinline__ float sigmoid_xla(float x) {
  return 0.5f + 0.5f * tanh_xla(0.5f * x);
}

__device__ __forceinline__ float soft_ternary(float v) {
  return 1.5f * tanh_xla(v) + 0.5f * tanh_xla(-3.0f * v);
}

__device__ __forceinline__ int ternary_digit(float v) {
  return (int)rintf(soft_ternary(v)) + 1;
}

// ---------------- K0: digit threshold finder (1 thread) ----------------
// Finds the smallest-float crossing th where rintf(soft(s)) reaches 1.
// soft is exactly odd in float, so the negative threshold is -th.
__global__ void k_thr(float* __restrict__ thr) {
  if (threadIdx.x == 0 && blockIdx.x == 0) {
    float lo = 0.0f, hi = 4.0f;  // digit(0)=0, digit(4)=1
    for (int i = 0; i < 64; ++i) {
      float mid = 0.5f * (lo + hi);
      if (rintf(soft_ternary(mid)) >= 1.0f) hi = mid; else lo = mid;
    }
    thr[0] = hi;  // smallest s found with digit == +1
  }
}

// ---------------- K1: obs encoder -> xcode[T*B] ----------------
__global__ __launch_bounds__(256)
__attribute__((amdgpu_waves_per_eu(1, 4)))  // ~110 live floats: never spill
void k_obs(
    const float* __restrict__ x,
    const float* __restrict__ w0, const float* __restrict__ b0,
    const float* __restrict__ w1, const float* __restrict__ b1,
    const float* __restrict__ w2, const float* __restrict__ b2,
    unsigned short* __restrict__ xcodes) {
  int e = blockIdx.x * 256 + threadIdx.x;  // grid is exact
  const float* xr = x + (size_t)e * 64;
  float xv[64];
#pragma unroll
  for (int j = 0; j < 64; j += 4) {
    float4 v = *reinterpret_cast<const float4*>(xr + j);
    xv[j] = v.x; xv[j + 1] = v.y; xv[j + 2] = v.z; xv[j + 3] = v.w;
  }
  float h1[28];
#pragma unroll
  for (int k = 0; k < 28; ++k) {
    float acc = 0.0f;
#pragma unroll
    for (int j = 0; j < 64; ++j) acc = fmaf(w0[k * 64 + j], xv[j], acc);
    h1[k] = tanh_xla(acc + b0[k]);
  }
  float h2[28];
#pragma unroll
  for (int k = 0; k < 28; ++k) {
    float acc = 0.0f;
#pragma unroll
    for (int j = 0; j < 28; ++j) acc = fmaf(w1[k * 28 + j], h1[j], acc);
    h2[k] = tanh_xla(acc + b1[k]);
  }
  const int p3[8] = {1, 3, 9, 27, 81, 243, 729, 2187};
  unsigned code = 0;
#pragma unroll
  for (int k = 0; k < 8; ++k) {
    float acc = 0.0f;
#pragma unroll
    for (int j = 0; j < 28; ++j) acc = fmaf(w2[k * 28 + j], h2[j], acc);
    code += (unsigned)(ternary_digit(acc + b2[k]) * p3[k]);
  }
  xcodes[e] = (unsigned short)code;
}

// ---------------- K2: GI table [6561][64] ----------------
__global__ __launch_bounds__(256) void k_gi(
    const float* __restrict__ wih, const float* __restrict__ bih,
    float* __restrict__ gip) {
  int c = blockIdx.x * 256 + threadIdx.x;
  if (c >= 6561) return;
  float q[8];
  unsigned cc = (unsigned)c;
#pragma unroll
  for (int k = 0; k < 8; ++k) { q[k] = (float)((int)(cc % 3u) - 1); cc /= 3u; }
#pragma unroll
  for (int i = 0; i < 16; ++i) {
    float gr = 0.f, gz = 0.f, gn = 0.f;
#pragma unroll
    for (int j = 0; j < 8; ++j) {
      gr = fmaf(wih[i * 8 + j], q[j], gr);
      gz = fmaf(wih[(16 + i) * 8 + j], q[j], gz);
      gn = fmaf(wih[(32 + i) * 8 + j], q[j], gn);
    }
    float4 o;
    o.x = gr + bih[i]; o.y = gz + bih[16 + i]; o.z = gn + bih[32 + i]; o.w = 0.f;
    *reinterpret_cast<float4*>(gip + (size_t)c * 64 + i * 4) = o;
  }
}

// ---------------- K3: GHM [6562][64] + Y [6561][16] ----------------
__global__ __launch_bounds__(256) void k_mtab(
    const float* __restrict__ q2m_w0, const float* __restrict__ q2m_b0,
    const float* __restrict__ q2m_w1, const float* __restrict__ q2m_b1,
    const float* __restrict__ q2m_w2, const float* __restrict__ q2m_b2,
    const float* __restrict__ whh, const float* __restrict__ bhh,
    const float* __restrict__ act_w, const float* __restrict__ act_b,
    float* __restrict__ ghm, float* __restrict__ ytab) {
  int c = blockIdx.x * 256 + threadIdx.x;
  if (c > 6561) return;
  float m[16];
  if (c == 6561) {
#pragma unroll
    for (int i = 0; i < 16; ++i) m[i] = 0.0f;  // h0 = 0
  } else {
    float q[8];
    unsigned cc = (unsigned)c;
#pragma unroll
    for (int k = 0; k < 8; ++k) { q[k] = (float)((int)(cc % 3u) - 1); cc /= 3u; }
    float a[16];
#pragma unroll
    for (int i = 0; i < 16; ++i) {
      float acc = 0.f;
#pragma unroll
      for (int j = 0; j < 8; ++j) acc = fmaf(q2m_w0[i * 8 + j], q[j], acc);
      a[i] = tanh_xla(acc + q2m_b0[i]);
    }
    float d[16];
#pragma unroll
    for (int i = 0; i < 16; ++i) {
      float acc = 0.f;
#pragma unroll
      for (int j = 0; j < 16; ++j) acc = fmaf(q2m_w1[i * 16 + j], a[j], acc);
      d[i] = tanh_xla(acc + q2m_b1[i]);
    }
#pragma unroll
    for (int i = 0; i < 16; ++i) {
      float acc = 0.f;
#pragma unroll
      for (int j = 0; j < 16; ++j) acc = fmaf(q2m_w2[i * 16 + j], d[j], acc);
      m[i] = tanh_xla(acc + q2m_b2[i]);
    }
  }
#pragma unroll
  for (int i = 0; i < 16; ++i) {
    float gr = 0.f, gz = 0.f, gn = 0.f;
#pragma unroll
    for (int j = 0; j < 16; ++j) {
      gr = fmaf(whh[i * 16 + j], m[j], gr);
      gz = fmaf(whh[(16 + i) * 16 + j], m[j], gz);
      gn = fmaf(whh[(32 + i) * 16 + j], m[j], gn);
    }
    float4 o;
    o.x = gr + bhh[i]; o.y = gz + bhh[16 + i]; o.z = gn + bhh[32 + i]; o.w = m[i];
    *reinterpret_cast<float4*>(ghm + (size_t)c * 64 + i * 4) = o;
  }
  if (c < 6561) {
#pragma unroll
    for (int i = 0; i < 16; ++i) {
      float acc = 0.f;
#pragma unroll
      for (int j = 0; j < 16; ++j) acc = fmaf(act_w[i * 16 + j], m[j], acc);
      ytab[(size_t)c * 16 + i] = tanh_xla(acc + act_b[i]);
    }
  }
}

// ---------------- K4: the scan. 16 lanes per batch element ----------------
// Force-batched 16-way broadcast: 16 ds_bpermute_b32 issued back-to-back into
// 16 DISTINCT registers (early-clobber outputs), one lgkmcnt(0) wait.
__device__ __forceinline__ void bperm16(int base4, float v, float* o) {
  asm volatile(
      "ds_bpermute_b32 %0, %16, %17 offset:0\n\t"
      "ds_bpermute_b32 %1, %16, %17 offset:4\n\t"
      "ds_bpermute_b32 %2, %16, %17 offset:8\n\t"
      "ds_bpermute_b32 %3, %16, %17 offset:12\n\t"
      "ds_bpermute_b32 %4, %16, %17 offset:16\n\t"
      "ds_bpermute_b32 %5, %16, %17 offset:20\n\t"
      "ds_bpermute_b32 %6, %16, %17 offset:24\n\t"
      "ds_bpermute_b32 %7, %16, %17 offset:28\n\t"
      "ds_bpermute_b32 %8, %16, %17 offset:32\n\t"
      "ds_bpermute_b32 %9, %16, %17 offset:36\n\t"
      "ds_bpermute_b32 %10, %16, %17 offset:40\n\t"
      "ds_bpermute_b32 %11, %16, %17 offset:44\n\t"
      "ds_bpermute_b32 %12, %16, %17 offset:48\n\t"
      "ds_bpermute_b32 %13, %16, %17 offset:52\n\t"
      "ds_bpermute_b32 %14, %16, %17 offset:56\n\t"
      "ds_bpermute_b32 %15, %16, %17 offset:60\n\t"
      "s_waitcnt lgkmcnt(0)"
      : "=&v"(o[0]), "=&v"(o[1]), "=&v"(o[2]), "=&v"(o[3]),
        "=&v"(o[4]), "=&v"(o[5]), "=&v"(o[6]), "=&v"(o[7]),
        "=&v"(o[8]), "=&v"(o[9]), "=&v"(o[10]), "=&v"(o[11]),
        "=&v"(o[12]), "=&v"(o[13]), "=&v"(o[14]), "=&v"(o[15])
      : "v"(base4), "v"(v));
}

// pre-loop VOLATILE opaque identity: cannot be sunk into the loop or
// duplicated (unlike R4's pure asm); its outputs are opaque values ->
// rematerializing the feeding loads inside the loop is illegal.
#define PIN8(a, b, c, d, e, f, g, h)                                        \
  asm volatile("" : "+v"(a), "+v"(b), "+v"(c), "+v"(d), "+v"(e), "+v"(f),   \
                    "+v"(g), "+v"(h))

// add the row_ror:<N>-moved copy of v (16-lane row rotation, VALU pipe)
#define DPP_ROR_ADD(v, CTRL)                                               \
  v += __int_as_float(__builtin_amdgcn_update_dpp(                         \
      0, __float_as_int(v), (CTRL), 0xF, 0xF, true))

__global__ __launch_bounds__(64)
__attribute__((amdgpu_waves_per_eu(1, 1)))  // occupancy target 1 wave/EU:
                                            // stop pressure-motivated remat
void k_scan(
    const unsigned short* __restrict__ xcodes,
    const float* __restrict__ ghm,  // [6562][64]
    const float* __restrict__ gip,  // [6561][64]
    const float* __restrict__ m2q_w0, const float* __restrict__ m2q_b0,
    const float* __restrict__ m2q_w1, const float* __restrict__ m2q_b1,
    const float* __restrict__ m2q_w2, const float* __restrict__ m2q_b2,
    const float* __restrict__ thr,
    unsigned short* __restrict__ qcodes) {
  int lane = threadIdx.x & 15;
  int b = (blockIdx.x * 64 + threadIdx.x) >> 4;  // 0..2047
  int base4 = (threadIdx.x & 48) << 2;           // bpermute byte addr of group lane 0
  int lane16 = lane * 16;                        // byte offset of this lane's float4

  // per-lane m2q weight rows
  float w0r[16], w1r[16], w2r[16];
#pragma unroll
  for (int j = 0; j < 16; j += 4) {
    float4 a = *reinterpret_cast<const float4*>(m2q_w0 + lane * 16 + j);
    w0r[j] = a.x; w0r[j + 1] = a.y; w0r[j + 2] = a.z; w0r[j + 3] = a.w;
    float4 bq = *reinterpret_cast<const float4*>(m2q_w1 + lane * 16 + j);
    w1r[j] = bq.x; w1r[j + 1] = bq.y; w1r[j + 2] = bq.z; w1r[j + 3] = bq.w;
    float4 cq = *reinterpret_cast<const float4*>(m2q_w2 + (lane & 7) * 16 + j);
    w2r[j] = cq.x; w2r[j + 1] = cq.y; w2r[j + 2] = cq.z; w2r[j + 3] = cq.w;
  }
  float b0l = m2q_b0[lane], b1l = m2q_b1[lane], b2l = m2q_b2[lane & 7];
  // digit weight: 3^(lane&7) * 256 as float (exact); zero on lanes 8..15 so a
  // full 16-lane rotate-reduce counts each digit exactly once
  int p3i = 1;
  for (int k = 0; k < (lane & 7); ++k) p3i *= 3;
  float w3f = (lane < 8) ? (float)(p3i * 256) : 0.0f;
  float thi = thr[0];  // digit threshold (positive side; soft exactly odd)
  const int kOffBias = 3280 * 256;  // sum of 3^k*256, k=0..7

  // ONE pre-loop volatile pin set. Volatile asm can't be sunk into the
  // loop or duplicated; outputs are opaque -> loads can't be remat'd inside
  // the loop (R5 proof: VGPR 44->132, -37us). Keeps the loop body free of
  // scheduler-barrier asms.
  PIN8(w0r[0], w0r[1], w0r[2], w0r[3], w0r[4], w0r[5], w0r[6], w0r[7]);
  PIN8(w0r[8], w0r[9], w0r[10], w0r[11], w0r[12], w0r[13], w0r[14], w0r[15]);
  PIN8(w1r[0], w1r[1], w1r[2], w1r[3], w1r[4], w1r[5], w1r[6], w1r[7]);
  PIN8(w1r[8], w1r[9], w1r[10], w1r[11], w1r[12], w1r[13], w1r[14], w1r[15]);
  PIN8(w2r[0], w2r[1], w2r[2], w2r[3], w2r[4], w2r[5], w2r[6], w2r[7]);
  PIN8(w2r[8], w2r[9], w2r[10], w2r[11], w2r[12], w2r[13], w2r[14], w2r[15]);
  asm volatile("" : "+v"(b0l), "+v"(b1l), "+v"(b2l), "+v"(w3f), "+v"(thi));

  const char* ghmB = (const char*)ghm;
  const char* gipB = (const char*)gip;

  int qoff = 6561 * 256;  // byte offset of initial-state row
  unsigned xc = xcodes[b];
  float4 i4 = *reinterpret_cast<const float4*>(gipB + (unsigned)(((int)xc << 8) + lane16));

  for (int t = 0; t < T_DIM; ++t) {
    float4 g4 = *reinterpret_cast<const float4*>(ghmB + (unsigned)(qoff + lane16));
    // prefetch next step's GI row (independent of qprev chain; t=511's
    // wrapped prefetch is computed but never consumed)
    int tn = (t + 1) & (T_DIM - 1);
    unsigned xcn = xcodes[tn * B_DIM + b];
    float4 i4n = *reinterpret_cast<const float4*>(gipB + (unsigned)(((int)xcn << 8) + lane16));

    float r = sigmoid_xla(i4.x + g4.x);
    float z = sigmoid_xla(i4.y + g4.y);
    float n = tanh_xla(fmaf(r, g4.z, i4.z));
    float h = (1.0f - z) * n + z * g4.w;

    // layer 0: one force-batched broadcast round, then the order-preserving
    // fma chain (identical arithmetic -> bit-exact)
    float hv[16];
    bperm16(base4, h, hv);
    float acc = 0.f;
#pragma unroll
    for (int j = 0; j < 16; ++j) acc = fmaf(w0r[j], hv[j], acc);
    float t0 = tanh_xla(acc + b0l);

    float tv0[16];
    bperm16(base4, t0, tv0);
    acc = 0.f;
#pragma unroll
    for (int j = 0; j < 16; ++j) acc = fmaf(w1r[j], tv0[j], acc);
    float t1 = tanh_xla(acc + b1l);

    float tv1[16];
    bperm16(base4, t1, tv1);
    acc = 0.f;
#pragma unroll
    for (int j = 0; j < 16; ++j) acc = fmaf(w2r[j], tv1[j], acc);

    // digit via thresholds: fast path = 2 compares; rintf(soft(s)) is a
    // monotone step in s (soft exactly odd); near-boundary waves
    // (| |s|-th | < 1e-3, ~3% of steps) recompute the exact rintf(soft)
    // for ALL lanes -> unconditionally bit-exact.
    float s = acc + b2l;
    float df = (s >= thi) ? 1.0f : ((s <= -thi) ? -1.0f : 0.0f);
    if (__builtin_expect(__any(fabsf(fabsf(s) - thi) < 1e-3f), 0)) {
      df = rintf(soft_ternary(s));
    }
    float st = df * w3f;  // in {-1,0,1} * 3^k*256 (0 on lanes 8..15)
    // exact-integer all-reduce across the 16-lane row: 4 DPP rotate+add rounds
    DPP_ROR_ADD(st, 0x128);  // row_ror:8
    DPP_ROR_ADD(st, 0x124);  // row_ror:4
    DPP_ROR_ADD(st, 0x122);  // row_ror:2
    DPP_ROR_ADD(st, 0x121);  // row_ror:1
    qoff = (int)st + kOffBias;  // byte offset = qcode*256

    if (lane == 0) qcodes[t * B_DIM + b] = (unsigned short)((unsigned)qoff >> 8);
    i4 = i4n;
  }
}

// ---------------- K5: output gather out[e] = Y[qcode[e]] ----------------
__global__ __launch_bounds__(256) void k_out(
    const unsigned short* __restrict__ qcodes,
    const float* __restrict__ ytab,
    float* __restrict__ out) {
  int i = blockIdx.x * 256 + threadIdx.x;  // over NELEM*4 float4s, grid exact
  int e = i >> 2, sub = i & 3;
  unsigned c = qcodes[e];
  float4 y = *reinterpret_cast<const float4*>(ytab + (size_t)c * 16 + sub * 4);
  reinterpret_cast<float4*>(out)[i] = y;
}

extern "C" void kernel_launch(void* const* d_in, const int* in_sizes, int n_in,
                              void* d_out, int out_size, void* d_ws, size_t ws_size,
                              hipStream_t stream) {
  (void)in_sizes; (void)n_in; (void)out_size; (void)ws_size;
  const float* x       = (const float*)d_in[0];
  const float* obs_w0  = (const float*)d_in[1];
  const float* obs_b0  = (const float*)d_in[2];
  const float* obs_w1  = (const float*)d_in[3];
  const float* obs_b1  = (const float*)d_in[4];
  const float* obs_w2  = (const float*)d_in[5];
  const float* obs_b2  = (const float*)d_in[6];
  const float* gru_wih = (const float*)d_in[7];
  const float* gru_whh = (const float*)d_in[8];
  const float* gru_bih = (const float*)d_in[9];
  const float* gru_bhh = (const float*)d_in[10];
  const float* m2q_w0  = (const float*)d_in[11];
  const float* m2q_b0  = (const float*)d_in[12];
  const float* m2q_w1  = (const float*)d_in[13];
  const float* m2q_b1  = (const float*)d_in[14];
  const float* m2q_w2  = (const float*)d_in[15];
  const float* m2q_b2  = (const float*)d_in[16];
  const float* q2m_w0  = (const float*)d_in[17];
  const float* q2m_b0  = (const float*)d_in[18];
  const float* q2m_w1  = (const float*)d_in[19];
  const float* q2m_b1  = (const float*)d_in[20];
  const float* q2m_w2  = (const float*)d_in[21];
  const float* q2m_b2  = (const float*)d_in[22];
  const float* act_w   = (const float*)d_in[23];
  const float* act_b   = (const float*)d_in[24];

  char* ws = (char*)d_ws;
  unsigned short* xcodes = (unsigned short*)(ws);                 // 2MB
  unsigned short* qcodes = (unsigned short*)(ws + (2u << 20));    // 2MB
  float* gip  = (float*)(ws + (4u << 20));                        // ~1.6MB
  float* ghm  = (float*)(ws + (6u << 20));                        // ~1.7MB
  float* ytab = (float*)(ws + (8u << 20));                        // ~0.41MB
  float* thr  = (float*)(ws + (8u << 20) + (512u << 10));         // 4B @8.5MB

  k_thr<<<1, 64, 0, stream>>>(thr);
  k_gi<<<26, 256, 0, stream>>>(gru_wih, gru_bih, gip);
  k_mtab<<<26, 256, 0, stream>>>(q2m_w0, q2m_b0, q2m_w1, q2m_b1, q2m_w2, q2m_b2,
                                 gru_whh, gru_bhh, act_w, act_b, ghm, ytab);
  k_obs<<<NELEM / 256, 256, 0, stream>>>(x, obs_w0, obs_b0, obs_w1, obs_b1,
                                         obs_w2, obs_b2, xcodes);
  k_scan<<<(B_DIM * 16) / 64, 64, 0, stream>>>(xcodes, ghm, gip,
                                               m2q_w0, m2q_b0, m2q_w1, m2q_b1,
                                               m2q_w2, m2q_b2, thr, qcodes);
  k_out<<<(NELEM * 4) / 256, 256, 0, stream>>>(qcodes, ytab, (float*)d_out);
}